// Round 1
// 33807.123 us; speedup vs baseline: 1.9069x; 1.9069x over previous
//
#include <hip/hip_runtime.h>
#include <math.h>

// ---------------------------------------------------------------------------
// StateSpaceModel: B=512 T=256 Z=128 X=64 R=1024 HT=HO=1024.
// Round theory: sequential chain was weight-refetch bound (fp32 weights
// re-read + re-converted to bf16 every step, ~280 MB/step through per-CU L2
// bandwidth, f2b VALU on the staging critical path). This version:
//   * converts ALL weight matrices to bf16 ONCE per call into d_ws (~12.9 MB)
//   * carries bf16 shadow copies of h (ping-pong) and z_t for GEMM A-operands
//     (fp32 h still carried for the elementwise GRU update -> bitwise-identical
//     numerics to the previous kernel)
//   * staging is now pure bf16 copies; k_zt/k_obs weight fragments are direct
//     16B u16x8 loads (no per-fragment cvt).
// ws layout (21.1 MB): hbuf fp32 x2 | Hbuf bf16 | GP fp32 | hb16 x2 | zb16 |
//                      bf16 weight cache.
// ---------------------------------------------------------------------------

typedef unsigned short u16;
typedef __bf16 bf16x8 __attribute__((ext_vector_type(8)));
typedef u16    u16x8  __attribute__((ext_vector_type(8)));
typedef float  f32x4  __attribute__((ext_vector_type(4)));

#define DI __device__ __forceinline__
#define LDS_STRIDE 72   // 64 + 8 pad: 16B-aligned, 2-way bank alias (free)

DI u16  f2b(float f){ union{float f; unsigned u;} c; c.f = f;
                      return (u16)((c.u + 0x7fffu + ((c.u>>16)&1u))>>16); }  // RNE
DI float b2f(u16 x){ union{unsigned u; float f;} c; c.u = ((unsigned)x)<<16; return c.f; }
DI float sigm (float x){ return 1.f/(1.f+expf(-x)); }
DI float softp(float x){ return (x>15.f)? x : log1pf(expf(x)); }

DI f32x4 mfma16(bf16x8 a, bf16x8 b, f32x4 c){
  return __builtin_amdgcn_mfma_f32_16x16x32_bf16(a,b,c,0,0,0);
}

// --- staging: 64x64 bf16 tile (row stride ld) -> LDS
DI void stage64(const u16* __restrict__ g, int ld, u16* l){
  int t = threadIdx.x;            // 256 threads
#pragma unroll
  for(int i=0;i<2;i++){
    int e = (t + i*256)*8;
    int r = e>>6, c = e&63;
    *(u16x8*)(l + r*LDS_STRIDE + c) = *(const u16x8*)(g + (size_t)r*ld + c);
  }
}

// load 8 consecutive bf16 weights (16B) -> fragment
DI bf16x8 ldw8b(const u16* __restrict__ g){
  return __builtin_bit_cast(bf16x8, *(const u16x8*)g);
}

DI bf16x8 ldfragS(const u16* l, int row, int ko, int stride){
  return __builtin_bit_cast(bf16x8, *(const u16x8*)(l + row*stride + ko));
}
DI bf16x8 ldfrag(const u16* l, int row, int ko){ return ldfragS(l, row, ko, LDS_STRIDE); }

// generic 64x64 block GEMM: acc += A[64,K] @ W[N=64,K]^T  (all bf16)
DI void gemm_block(const u16* __restrict__ A, int lda,
                   const u16* __restrict__ W, int ldw, int K,
                   u16* lA, u16* lB, f32x4 acc[2][2],
                   int l16, int quad, int wm, int wn)
{
  for(int k0=0;k0<K;k0+=64){
    __syncthreads();
    stage64(A + k0, lda, lA);
    stage64(W + k0, ldw, lB);
    __syncthreads();
#pragma unroll
    for(int kc=0;kc<2;kc++){
      int ko = kc*32 + quad*8;
      bf16x8 a0 = ldfrag(lA, wm*32      + l16, ko);
      bf16x8 a1 = ldfrag(lA, wm*32 + 16 + l16, ko);
      bf16x8 b0 = ldfrag(lB, wn*32      + l16, ko);
      bf16x8 b1 = ldfrag(lB, wn*32 + 16 + l16, ko);
      acc[0][0] = mfma16(a0,b0,acc[0][0]);
      acc[0][1] = mfma16(a0,b1,acc[0][1]);
      acc[1][0] = mfma16(a1,b0,acc[1][0]);
      acc[1][1] = mfma16(a1,b1,acc[1][1]);
    }
  }
}

// ---------------- one-time fp32 -> bf16 weight conversion -------------------
__global__ __launch_bounds__(256) void k_cvt(const float* __restrict__ s,
                                             u16* __restrict__ d){
  int i = (blockIdx.x*256 + threadIdx.x)*8;
  f32x4 p0 = *(const f32x4*)(s+i), p1 = *(const f32x4*)(s+i+4);
  u16x8 o;
  o[0]=f2b(p0[0]); o[1]=f2b(p0[1]); o[2]=f2b(p0[2]); o[3]=f2b(p0[3]);
  o[4]=f2b(p1[0]); o[5]=f2b(p1[1]); o[6]=f2b(p1[2]); o[7]=f2b(p1[3]);
  *(u16x8*)(d+i) = o;
}

// ------------------------- init: broadcast h_0, z_0 -------------------------
__global__ __launch_bounds__(256) void k_init(float* __restrict__ hbuf,
                                              u16* __restrict__ hb,
                                              u16* __restrict__ zb,
                                              const float* __restrict__ h0,
                                              const float* __restrict__ z0){
  int idx = blockIdx.x*256 + threadIdx.x;           // 2048 blocks -> 524288
  float h = h0[idx & 1023];
  hbuf[idx] = h;
  hb[idx]   = f2b(h);
  if(idx < 512*128) zb[idx] = f2b(z0[idx & 127]);
}

// ------------------------- GRU cell (fused) ---------------------------------
// grid (16,8): bx = n-tile over R=1024, by = m-tile over B=512
__global__ __launch_bounds__(256) void k_gru(
  const u16*  __restrict__ zb,            // [512,128] bf16 A (ph0)
  const float* __restrict__ hin,          // fp32 h (elementwise)
  const u16*  __restrict__ hbin,          // [512,1024] bf16 A (ph1)
  float* __restrict__ hout,
  u16*   __restrict__ hbout,
  const u16* __restrict__ wih, const float* __restrict__ bih,
  const u16* __restrict__ whh, const float* __restrict__ bhh)
{
  __shared__ u16 lA[64*LDS_STRIDE];
  __shared__ u16 lB[3][64*LDS_STRIDE];
  const int m0 = blockIdx.y*64, n0 = blockIdx.x*64;
  const int lane = threadIdx.x & 63, w = threadIdx.x >> 6;
  const int l16 = lane & 15, quad = lane >> 4, wm = w>>1, wn = w&1;

  f32x4 acc[4][2][2] = {};   // 0=r, 1=z, 2=i_n, 3=h_n

#pragma unroll 1
  for(int ph=0; ph<2; ph++){
    const u16* Ab = ph ? hbin + (size_t)m0*1024 : zb + (size_t)m0*128;
    const u16* Wb = ph ? whh  + (size_t)n0*1024 : wih + (size_t)n0*128;
    const int lda = ph ? 1024 : 128;
    const int ldw = ph ? 1024 : 128;
    const int K   = ph ? 1024 : 128;
    const int ai3 = ph ? 3 : 2;
    for(int k0=0;k0<K;k0+=64){
      __syncthreads();
      stage64(Ab + k0, lda, lA);
      stage64(Wb + k0,                     ldw, lB[0]);
      stage64(Wb + (size_t)1024*ldw + k0,  ldw, lB[1]);
      stage64(Wb + (size_t)2048*ldw + k0,  ldw, lB[2]);
      __syncthreads();
#pragma unroll
      for(int kc=0;kc<2;kc++){
        int ko = kc*32 + quad*8;
        bf16x8 a0 = ldfrag(lA, wm*32      + l16, ko);
        bf16x8 a1 = ldfrag(lA, wm*32 + 16 + l16, ko);
#pragma unroll
        for(int s=0;s<3;s++){
          int ai = (s==2) ? ai3 : s;
          bf16x8 b0 = ldfrag(lB[s], wn*32      + l16, ko);
          bf16x8 b1 = ldfrag(lB[s], wn*32 + 16 + l16, ko);
          acc[ai][0][0] = mfma16(a0,b0,acc[ai][0][0]);
          acc[ai][0][1] = mfma16(a0,b1,acc[ai][0][1]);
          acc[ai][1][0] = mfma16(a1,b0,acc[ai][1][0]);
          acc[ai][1][1] = mfma16(a1,b1,acc[ai][1][1]);
        }
      }
    }
  }

#pragma unroll
  for(int mi=0;mi<2;mi++)
#pragma unroll
  for(int ni=0;ni<2;ni++)
#pragma unroll
  for(int i=0;i<4;i++){
    int m = m0 + wm*32 + mi*16 + quad*4 + i;
    int n = n0 + wn*32 + ni*16 + l16;
    float r  = sigm (acc[0][mi][ni][i] + bih[n]      + bhh[n]);
    float z  = sigm (acc[1][mi][ni][i] + bih[n+1024] + bhh[n+1024]);
    float nn = tanhf(acc[2][mi][ni][i] + bih[n+2048]
                     + r*(acc[3][mi][ni][i] + bhh[n+2048]));
    float h  = hin[(size_t)m*1024 + n];
    float hv = (1.f-z)*nn + z*h;
    hout [(size_t)m*1024 + n] = hv;
    hbout[(size_t)m*1024 + n] = f2b(hv);
  }
}

// ------------- trans hidden GEMM: C = act(A @ W^T + b), 3 regions -----------
// n0<1024: tgw relu | n0<2048: tpw relu | else tlw no-act. grid (34,8).
__global__ __launch_bounds__(256) void k_mlp3(
  const u16* __restrict__ A,
  const u16* __restrict__ W0, const float* __restrict__ B0,
  const u16* __restrict__ W1, const float* __restrict__ B1,
  const u16* __restrict__ W2, const float* __restrict__ B2,
  u16* __restrict__ C)
{
  __shared__ u16 lA[64*LDS_STRIDE], lB[64*LDS_STRIDE];
  const int m0 = blockIdx.y*64, n0 = blockIdx.x*64;
  const int lane = threadIdx.x & 63, w = threadIdx.x >> 6;
  const int l16 = lane & 15, quad = lane >> 4, wm = w>>1, wn = w&1;
  const u16 *W; const float *bias; int act = 1;
  if      (n0 < 1024) { W = W0 + (size_t)n0*1024;        bias = B0 + n0; }
  else if (n0 < 2048) { W = W1 + (size_t)(n0-1024)*1024; bias = B1 + (n0-1024); }
  else                { W = W2 + (size_t)(n0-2048)*1024; bias = B2 + (n0-2048); act = 0; }

  f32x4 acc[2][2] = {};
  gemm_block(A + (size_t)m0*1024, 1024, W, 1024, 1024, lA, lB, acc, l16, quad, wm, wn);

#pragma unroll
  for(int mi=0;mi<2;mi++)
#pragma unroll
  for(int ni=0;ni<2;ni++)
#pragma unroll
  for(int i=0;i<4;i++){
    int m  = m0 + wm*32 + mi*16 + quad*4 + i;
    int cl = wn*32 + ni*16 + l16;
    float v = acc[mi][ni][i] + bias[cl];
    if(act) v = fmaxf(v, 0.f);
    C[(size_t)m*2176 + n0 + cl] = f2b(v);
  }
}

// --------- gate/prop GEMM, fp32 out [512,256]: grid (4,8) -------------------
// n0<128: gate = gate_h @ tghzw^T ; else prop = prop_h @ tphzw^T (A col +1024)
__global__ __launch_bounds__(256) void k_gp(
  const u16* __restrict__ H,
  const u16* __restrict__ W0, const float* __restrict__ B0,
  const u16* __restrict__ W1, const float* __restrict__ B1,
  float* __restrict__ C)
{
  __shared__ u16 lA[64*LDS_STRIDE], lB[64*LDS_STRIDE];
  const int m0 = blockIdx.y*64, n0 = blockIdx.x*64;
  const int lane = threadIdx.x & 63, w = threadIdx.x >> 6;
  const int l16 = lane & 15, quad = lane >> 4, wm = w>>1, wn = w&1;
  const int reg1 = (n0 >= 128);
  const u16*  A   = H + (size_t)m0*2176 + (reg1 ? 1024 : 0);
  const u16*  W   = reg1 ? W1 + (size_t)(n0-128)*1024 : W0 + (size_t)n0*1024;
  const float* bias = reg1 ? B1 + (n0-128)            : B0 + n0;

  f32x4 acc[2][2] = {};
  gemm_block(A, 2176, W, 1024, 1024, lA, lB, acc, l16, quad, wm, wn);

#pragma unroll
  for(int mi=0;mi<2;mi++)
#pragma unroll
  for(int ni=0;ni<2;ni++)
#pragma unroll
  for(int i=0;i<4;i++){
    int m  = m0 + wm*32 + mi*16 + quad*4 + i;
    int cl = wn*32 + ni*16 + l16;
    C[(size_t)m*256 + n0 + cl] = acc[mi][ni][i] + bias[cl];
  }
}

// ------------- z_t: scale GEMM (K=128) + reparam; z -> out[b,t,0:128] -------
// also writes bf16 z copy (zb) for next step's GRU A-operand.
__global__ __launch_bounds__(256) void k_zt(
  const float* __restrict__ GP, const u16* __restrict__ H,
  const u16* __restrict__ sw, const float* __restrict__ sb,
  const float* __restrict__ eps, float* __restrict__ zout,
  u16* __restrict__ zb, int tstep)
{
  __shared__ u16 lp[64*136];          // relu(proposed) 64x128 bf16, +8 pad
  const int m0 = blockIdx.x*64;
  const int t  = threadIdx.x;
#pragma unroll
  for(int i=0;i<32;i++){
    int e = t + i*256;
    int r = e>>7, c = e&127;
    float p = GP[(size_t)(m0+r)*256 + 128 + c];
    lp[r*136 + c] = f2b(fmaxf(p, 0.f));
  }
  __syncthreads();
  const int lane = t & 63, w = t >> 6, l16 = lane & 15, quad = lane >> 4;
  f32x4 acc[8] = {};
#pragma unroll
  for(int kc=0;kc<4;kc++){
    int ko = kc*32 + quad*8;
    bf16x8 a = ldfragS(lp, w*16+l16, ko, 136);
#pragma unroll
    for(int nf=0;nf<8;nf++){
      bf16x8 b = ldw8b(sw + (size_t)(nf*16+l16)*128 + ko);
      acc[nf] = mfma16(a, b, acc[nf]);
    }
  }
#pragma unroll
  for(int nf=0;nf<8;nf++)
#pragma unroll
  for(int i=0;i<4;i++){
    int gm  = m0 + w*16 + quad*4 + i;
    int col = nf*16 + l16;
    float zs  = softp(acc[nf][i] + sb[col]);
    float g   = sigm(GP[(size_t)gm*256 + col]);
    float pv  = GP[(size_t)gm*256 + 128 + col];
    float loc = b2f(H[(size_t)gm*2176 + 2048 + col]);
    float zl  = (1.f-g)*loc + g*pv;
    float e   = eps[(size_t)gm*32768 + (size_t)tstep*128 + col];
    float zv  = zl + zs*e;
    zout[(size_t)gm*32768 + (size_t)tstep*128 + col] = zv;
    zb[(size_t)gm*128 + col] = f2b(zv);
  }
}

// ------------------- FUSED obs branch: one block = 32 rows ------------------
// grid 4096. Reads z (fp32) from out[b,t,0:128], overwrites with x_loc|x_scale.
// LDS: lz 8.7KB + lh 33.3KB + lp 4.6KB = 46.6KB (<64KB/WG).
#define LH_S 520
__global__ __launch_bounds__(256) void k_obs(
  const u16* __restrict__ ogw,   const float* __restrict__ ogb,
  const u16* __restrict__ oghzw, const float* __restrict__ oghzb,
  const u16* __restrict__ opw,   const float* __restrict__ opb,
  const u16* __restrict__ ophzw, const float* __restrict__ ophzb,
  const u16* __restrict__ olw,   const float* __restrict__ olb,
  const u16* __restrict__ osw,   const float* __restrict__ osb,
  float* __restrict__ out)
{
  __shared__ u16 lz[32*136];
  __shared__ u16 lh[32*LH_S];
  __shared__ u16 lp[32*72];
  const int r0 = blockIdx.x*32;
  const int t  = r0 >> 9, b0 = r0 & 511;        // 32 | 512 -> single t per block
  const int tid = threadIdx.x;
  const int lane = tid & 63, w = tid>>6, l16 = lane&15, quad = lane>>4;

  // stage z (32 x 128) fp32 -> bf16
#pragma unroll
  for(int i=0;i<2;i++){
    int ch = tid + i*256;
    int r = ch>>4, c = (ch&15)*8;
    const float* src = out + (size_t)(b0+r)*32768 + (size_t)t*128 + c;
    f32x4 p0 = *(const f32x4*)src, p1 = *(const f32x4*)(src+4);
    u16x8 o;
    o[0]=f2b(p0[0]); o[1]=f2b(p0[1]); o[2]=f2b(p0[2]); o[3]=f2b(p0[3]);
    o[4]=f2b(p1[0]); o[5]=f2b(p1[1]); o[6]=f2b(p1[2]); o[7]=f2b(p1[3]);
    *(u16x8*)(lz + r*136 + c) = o;
  }
  __syncthreads();

  f32x4 accp[2] = {}, accg[2] = {};
  const int col = w*16 + l16;                   // this wave's output column

#pragma unroll 1
  for(int ph=0; ph<2; ph++){                    // 0 = prop path, 1 = gate path
    const u16* hw = ph ? ogw   : opw;
    const float* hb = ph ? ogb : opb;
    const u16* zw = ph ? oghzw : ophzw;
    f32x4* acc2    = ph ? accg : accp;
#pragma unroll 1
    for(int c2=0; c2<2; c2++){                  // hidden cols [c2*512, +512)
      __syncthreads();                          // protect lh from prior readers
      for(int nt = w; nt < 32; nt += 4){
        int n = c2*512 + nt*16 + l16;           // hidden unit = weight row
#pragma unroll
        for(int mi=0; mi<2; mi++){
          f32x4 a = {};
#pragma unroll
          for(int kc=0;kc<4;kc++){
            int ko = kc*32 + quad*8;
            a = mfma16(ldfragS(lz, mi*16+l16, ko, 136),
                       ldw8b(hw + (size_t)n*128 + ko), a);
          }
          float bias = hb[n];
#pragma unroll
          for(int i=0;i<4;i++)
            lh[(mi*16+quad*4+i)*LH_S + nt*16 + l16] = f2b(fmaxf(a[i]+bias, 0.f));
        }
      }
      __syncthreads();
      // hz GEMM: accumulate K chunk [c2*512, +512) for output col `col`
#pragma unroll
      for(int mi=0;mi<2;mi++){
        f32x4 a = acc2[mi];
        for(int kc=0;kc<16;kc++){
          int ko = kc*32 + quad*8;
          a = mfma16(ldfragS(lh, mi*16+l16, ko, LH_S),
                     ldw8b(zw + (size_t)col*1024 + c2*512 + ko), a);
        }
        acc2[mi] = a;
      }
    }
    if(ph==0){
      float bias = ophzb[col];
#pragma unroll
      for(int mi=0;mi<2;mi++)
#pragma unroll
      for(int i=0;i<4;i++){
        float pv = accp[mi][i] + bias;          // proposed incl. bias
        accp[mi][i] = pv;
        lp[(mi*16+quad*4+i)*72 + col] = f2b(fmaxf(pv, 0.f));
      }
      // lp becomes visible via the barriers inside ph=1's c2 loop
    }
  }

  // loc (K=128, A=lz) and scale (K=64, A=lp) GEMMs for column `col`
  f32x4 accl[2]={}, accs[2]={};
#pragma unroll
  for(int mi=0;mi<2;mi++){
#pragma unroll
    for(int kc=0;kc<4;kc++){
      int ko=kc*32+quad*8;
      accl[mi]=mfma16(ldfragS(lz,mi*16+l16,ko,136),
                      ldw8b(olw + (size_t)col*128 + ko), accl[mi]);
    }
#pragma unroll
    for(int kc=0;kc<2;kc++){
      int ko=kc*32+quad*8;
      accs[mi]=mfma16(ldfragS(lp,mi*16+l16,ko,72),
                      ldw8b(osw + (size_t)col*64 + ko), accs[mi]);
    }
  }
#pragma unroll
  for(int mi=0;mi<2;mi++)
#pragma unroll
  for(int i=0;i<4;i++){
    int r = mi*16 + quad*4 + i;
    float g  = sigm(accg[mi][i] + oghzb[col]);
    float pv = accp[mi][i];
    float lc = accl[mi][i] + olb[col];
    float xs = softp(accs[mi][i] + osb[col]);
    float xl = (1.f-g)*lc + g*pv;
    size_t o = (size_t)(b0+r)*32768 + (size_t)t*128 + col;
    out[o]      = xl;
    out[o + 64] = xs;
  }
}

// ---------------------------------------------------------------------------
extern "C" void kernel_launch(void* const* d_in, const int* in_sizes, int n_in,
                              void* d_out, int out_size, void* d_ws, size_t ws_size,
                              hipStream_t stream)
{
  (void)in_sizes; (void)n_in; (void)out_size; (void)ws_size;
  const float* eps   = (const float*)d_in[1];
  const float* z0    = (const float*)d_in[2];
  const float* h0    = (const float*)d_in[3];
  const float* gwih  = (const float*)d_in[4];  const float* gbih  = (const float*)d_in[5];
  const float* gwhh  = (const float*)d_in[6];  const float* gbhh  = (const float*)d_in[7];
  const float* tgw   = (const float*)d_in[8];  const float* tgb   = (const float*)d_in[9];
  const float* tghzw = (const float*)d_in[10]; const float* tghzb = (const float*)d_in[11];
  const float* tpw   = (const float*)d_in[12]; const float* tpb   = (const float*)d_in[13];
  const float* tphzw = (const float*)d_in[14]; const float* tphzb = (const float*)d_in[15];
  const float* tlw   = (const float*)d_in[16]; const float* tlb   = (const float*)d_in[17];
  const float* tsw   = (const float*)d_in[18]; const float* tsb   = (const float*)d_in[19];
  const float* ogw   = (const float*)d_in[20]; const float* ogb   = (const float*)d_in[21];
  const float* oghzw = (const float*)d_in[22]; const float* oghzb = (const float*)d_in[23];
  const float* opw   = (const float*)d_in[24]; const float* opb   = (const float*)d_in[25];
  const float* ophzw = (const float*)d_in[26]; const float* ophzb = (const float*)d_in[27];
  const float* olw   = (const float*)d_in[28]; const float* olb   = (const float*)d_in[29];
  const float* osw   = (const float*)d_in[30]; const float* osb   = (const float*)d_in[31];
  float* out = (float*)d_out;

  // ---- ws layout (21.1 MB total) ----
  char* ws = (char*)d_ws;
  size_t off = 0;
  float* hbuf = (float*)(ws + off); off += (size_t)2*512*1024*4;   // 4.19 MB
  u16*   Hbuf = (u16*)  (ws + off); off += (size_t)512*2176*2;     // 2.23 MB
  float* GP   = (float*)(ws + off); off += (size_t)512*256*4;      // 0.52 MB
  u16*   hb16 = (u16*)  (ws + off); off += (size_t)2*512*1024*2;   // 2.10 MB
  u16*   zb16 = (u16*)  (ws + off); off += (size_t)512*128*2;      // 0.13 MB
  // bf16 weight cache (12.9 MB)
  u16* wc_gwih  = (u16*)(ws + off); off += (size_t)3072*128 *2;
  u16* wc_gwhh  = (u16*)(ws + off); off += (size_t)3072*1024*2;
  u16* wc_tgw   = (u16*)(ws + off); off += (size_t)1024*1024*2;
  u16* wc_tpw   = (u16*)(ws + off); off += (size_t)1024*1024*2;
  u16* wc_tlw   = (u16*)(ws + off); off += (size_t)128*1024 *2;
  u16* wc_tghzw = (u16*)(ws + off); off += (size_t)128*1024 *2;
  u16* wc_tphzw = (u16*)(ws + off); off += (size_t)128*1024 *2;
  u16* wc_tsw   = (u16*)(ws + off); off += (size_t)128*128  *2;
  u16* wc_ogw   = (u16*)(ws + off); off += (size_t)1024*128 *2;
  u16* wc_opw   = (u16*)(ws + off); off += (size_t)1024*128 *2;
  u16* wc_oghzw = (u16*)(ws + off); off += (size_t)64*1024  *2;
  u16* wc_ophzw = (u16*)(ws + off); off += (size_t)64*1024  *2;
  u16* wc_olw   = (u16*)(ws + off); off += (size_t)64*128   *2;
  u16* wc_osw   = (u16*)(ws + off); off += (size_t)64*64    *2;

  // ---- one-time weight conversion (per call; inputs may be re-poisoned) ----
  #define CVT(src, dst, n) k_cvt<<<(n)/2048, 256, 0, stream>>>((src), (dst))
  CVT(gwih,  wc_gwih,  3072*128);
  CVT(gwhh,  wc_gwhh,  3072*1024);
  CVT(tgw,   wc_tgw,   1024*1024);
  CVT(tpw,   wc_tpw,   1024*1024);
  CVT(tlw,   wc_tlw,   128*1024);
  CVT(tghzw, wc_tghzw, 128*1024);
  CVT(tphzw, wc_tphzw, 128*1024);
  CVT(tsw,   wc_tsw,   128*128);
  CVT(ogw,   wc_ogw,   1024*128);
  CVT(opw,   wc_opw,   1024*128);
  CVT(oghzw, wc_oghzw, 64*1024);
  CVT(ophzw, wc_ophzw, 64*1024);
  CVT(olw,   wc_olw,   64*128);
  CVT(osw,   wc_osw,   64*64);
  #undef CVT

  k_init<<<2048, 256, 0, stream>>>(hbuf, hb16, zb16, h0, z0);

  for(int t=0; t<256; t++){
    const float* hin  = hbuf + (size_t)(t&1)*524288;
    float*       hout = hbuf + (size_t)((t+1)&1)*524288;
    const u16*   hbi  = hb16 + (size_t)(t&1)*524288;
    u16*         hbo  = hb16 + (size_t)((t+1)&1)*524288;
    k_gru <<<dim3(16,8), 256, 0, stream>>>(zb16, hin, hbi, hout, hbo,
                                           wc_gwih, gbih, wc_gwhh, gbhh);
    k_mlp3<<<dim3(34,8), 256, 0, stream>>>(hbo, wc_tgw, tgb, wc_tpw, tpb,
                                           wc_tlw, tlb, Hbuf);
    k_gp  <<<dim3(4,8),  256, 0, stream>>>(Hbuf, wc_tghzw, tghzb, wc_tphzw, tphzb, GP);
    k_zt  <<<dim3(8),    256, 0, stream>>>(GP, Hbuf, wc_tsw, tsb, eps, out, zb16, t);
  }

  // fused obs: reads z from out slices, overwrites them with x_loc|x_scale
  k_obs<<<4096, 256, 0, stream>>>(wc_ogw, ogb, wc_oghzw, oghzb,
                                  wc_opw, opb, wc_ophzw, ophzb,
                                  wc_olw, olb, wc_osw, osb, out);
}

// Round 3
// 26706.064 us; speedup vs baseline: 2.4139x; 1.2659x over previous
//
#include <hip/hip_runtime.h>
#include <math.h>

// ---------------------------------------------------------------------------
// StateSpaceModel: B=512 T=256 Z=128 X=64 R=1024 HT=HO=1024.
// R3: persistent kernel with SOFTWARE grid barrier (R2's cooperative launch
// silently no-op'd under graph capture -> absmax 0.52 = "recurrence never ran").
//  - ordinary <<<512,256>>> launch; co-residency guaranteed: 256 CU x 2 blocks
//    (__launch_bounds__(256,2), LDS 36.9KB/block -> 2/CU, VGPR << 256).
//  - sense-reversing generation barrier in ws; agent-scope fences
//    (buffer_wbl2/buffer_inv) for cross-XCD visibility of plain stores.
//  - phases rebalanced to 1 tile/block: P1 GRU 512t(18it) | P2 gate+prop
//    hidden 512t(16it) | P3 GP-gemm 128t + loc 32t (16it) | P4 zt 64t(1it).
//  - double-buffered LDS in all K-loops: stage(k+1) overlaps compute(k),
//    one barrier per iter.
//  - accumulation order per output element identical to R1 -> same numerics.
// ---------------------------------------------------------------------------

typedef unsigned short u16;
typedef __bf16 bf16x8 __attribute__((ext_vector_type(8)));
typedef u16    u16x8  __attribute__((ext_vector_type(8)));
typedef float  f32x4  __attribute__((ext_vector_type(4)));

#define DI __device__ __forceinline__
#define LDS_STRIDE 72   // 64 + 8 pad: 16B-aligned, 2-way bank alias (free)

DI u16  f2b(float f){ union{float f; unsigned u;} c; c.f = f;
                      return (u16)((c.u + 0x7fffu + ((c.u>>16)&1u))>>16); }  // RNE
DI float b2f(u16 x){ union{unsigned u; float f;} c; c.u = ((unsigned)x)<<16; return c.f; }
DI float sigm (float x){ return 1.f/(1.f+expf(-x)); }
DI float softp(float x){ return (x>15.f)? x : log1pf(expf(x)); }

DI f32x4 mfma16(bf16x8 a, bf16x8 b, f32x4 c){
  return __builtin_amdgcn_mfma_f32_16x16x32_bf16(a,b,c,0,0,0);
}
DI bf16x8 ldw8b(const u16* __restrict__ g){
  return __builtin_bit_cast(bf16x8, *(const u16x8*)g);
}
DI bf16x8 ldfragS(const u16* l, int row, int ko, int stride){
  return __builtin_bit_cast(bf16x8, *(const u16x8*)(l + row*stride + ko));
}
DI bf16x8 ldfrag(const u16* l, int row, int ko){ return ldfragS(l, row, ko, LDS_STRIDE); }

// ---- software grid barrier (512 blocks co-resident by construction) --------
DI void gsync(unsigned* cnt, unsigned* gen){
  __syncthreads();
  if(threadIdx.x == 0){
    __builtin_amdgcn_fence(__ATOMIC_RELEASE, "agent");   // wb L2 (dirty lines)
    unsigned g = __hip_atomic_load(gen, __ATOMIC_RELAXED, __HIP_MEMORY_SCOPE_AGENT);
    unsigned v = __hip_atomic_fetch_add(cnt, 1u, __ATOMIC_RELAXED, __HIP_MEMORY_SCOPE_AGENT);
    if(v == 511u){
      __hip_atomic_store(cnt, 0u,  __ATOMIC_RELAXED, __HIP_MEMORY_SCOPE_AGENT);
      __hip_atomic_store(gen, g+1u, __ATOMIC_RELEASE, __HIP_MEMORY_SCOPE_AGENT);
    } else {
      while(__hip_atomic_load(gen, __ATOMIC_RELAXED, __HIP_MEMORY_SCOPE_AGENT) == g)
        __builtin_amdgcn_s_sleep(2);
    }
    __builtin_amdgcn_fence(__ATOMIC_ACQUIRE, "agent");   // inv stale L2 lines
  }
  __syncthreads();
}

// ---------------- one-time fp32 -> bf16 weight conversion -------------------
__global__ __launch_bounds__(256) void k_cvt(const float* __restrict__ s,
                                             u16* __restrict__ d){
  int i = (blockIdx.x*256 + threadIdx.x)*8;
  f32x4 p0 = *(const f32x4*)(s+i), p1 = *(const f32x4*)(s+i+4);
  u16x8 o;
  o[0]=f2b(p0[0]); o[1]=f2b(p0[1]); o[2]=f2b(p0[2]); o[3]=f2b(p0[3]);
  o[4]=f2b(p1[0]); o[5]=f2b(p1[1]); o[6]=f2b(p1[2]); o[7]=f2b(p1[3]);
  *(u16x8*)(d+i) = o;
}

__global__ void k_bzero(unsigned* b){ if(threadIdx.x==0){ b[0]=0u; b[32]=0u; } }

// ------------------------- persistent sequential kernel ---------------------
struct SeqP {
  const float *eps, *h0, *z0;
  const float *gbih, *gbhh, *tgb, *tpb, *tlb, *tghzb, *tphzb, *tsb;
  const u16 *wih, *whh, *tgw, *tpw, *tlw, *tghzw, *tphzw, *tsw;
  float *out, *hbuf, *GP;
  u16 *Hbuf, *hb16, *zb16;
  unsigned *bcnt, *bgen;
};

// 32m x 64n x K=1024 tile: C = act(A @ W^T + b); dbuf; smem needs 2x6912 u16
DI void mlp_tile(const u16* __restrict__ A,      // + m0*1024 applied by caller
                 const u16* __restrict__ W,      // 64 region rows x 1024
                 const float* __restrict__ bias, int act,
                 u16* __restrict__ Cb,           // Hbuf + m0*2176 + n0
                 u16* smem, int tid)
{
  const int lane=tid&63, w=tid>>6, l16=lane&15, quad=lane>>4, wm=w>>1, wn=w&1;
  const int ar=tid>>3, ac=(tid&7)*8, br=tid>>2, bc=(tid&3)*16;
  f32x4 acc[2] = {};
#pragma unroll 1
  for(int it=-1; it<16; ++it){
    int is = it+1;
    if(is < 16){
      u16* b = smem + (is&1)*6912;
      *(u16x8*)(b + ar*LDS_STRIDE + ac) =
        *(const u16x8*)(A + (size_t)ar*1024 + is*64 + ac);
      u16* lb = b + 2304;
      *(u16x8*)(lb + br*LDS_STRIDE + bc) =
        *(const u16x8*)(W + (size_t)br*1024 + is*64 + bc);
      *(u16x8*)(lb + br*LDS_STRIDE + bc + 8) =
        *(const u16x8*)(W + (size_t)br*1024 + is*64 + bc + 8);
    }
    if(it >= 0){
      u16* c = smem + (it&1)*6912;
#pragma unroll
      for(int kc=0;kc<2;kc++){
        int ko = kc*32 + quad*8;
        bf16x8 a  = ldfrag(c, wm*16 + l16, ko);
        bf16x8 b0 = ldfrag(c + 2304, wn*32 + l16, ko);
        bf16x8 b1 = ldfrag(c + 2304, wn*32 + 16 + l16, ko);
        acc[0] = mfma16(a, b0, acc[0]);
        acc[1] = mfma16(a, b1, acc[1]);
      }
    }
    __syncthreads();
  }
#pragma unroll
  for(int nf=0; nf<2; nf++)
#pragma unroll
  for(int i=0; i<4; i++){
    int m  = wm*16 + quad*4 + i;
    int cl = wn*32 + nf*16 + l16;
    float v = acc[nf][i] + bias[cl];
    if(act) v = fmaxf(v, 0.f);
    Cb[(size_t)m*2176 + cl] = f2b(v);
  }
}

__global__ __launch_bounds__(256, 2) void k_seq(SeqP p)
{
  __shared__ u16 smem[18432];                   // 36.9 KB (2 dbuf x 9216)
  const int blk  = blockIdx.x;                  // 0..511
  const int tid  = threadIdx.x;
  const int lane = tid & 63, w = tid >> 6;
  const int l16  = lane & 15, quad = lane >> 4;
  const int wm   = w >> 1, wn = w & 1;
  const int ar   = tid >> 3, ac = (tid & 7) * 8;   // 32-row tile staging

  // ---- init: broadcast h_0 (fp32 + bf16) and z_0 (bf16) ----
  for(int i = blk*256 + tid; i < 512*1024; i += 512*256){
    float h = p.h0[i & 1023];
    p.hbuf[i] = h;
    p.hb16[i] = f2b(h);
  }
  for(int i = blk*256 + tid; i < 512*128; i += 512*256)
    p.zb16[i] = f2b(p.z0[i & 127]);
  gsync(p.bcnt, p.bgen);

#pragma unroll 1
  for(int t = 0; t < 256; t++){
    const float* hin  = p.hbuf + (size_t)(t&1)*524288;
    float*       hout = p.hbuf + (size_t)((t+1)&1)*524288;
    const u16*   hbi  = p.hb16 + (size_t)(t&1)*524288;
    u16*         hbo  = p.hb16 + (size_t)((t+1)&1)*524288;

    // ========== P1: GRU, 512 tiles 32m x 32n x 3 gates, 18 iters dbuf ======
    {
      const int m0 = (blk >> 5) * 32;
      const int n0 = (blk & 31) * 32;
      f32x4 acc[4] = {};              // 0=r, 1=z, 2=i_n, 3=h_n
#pragma unroll 1
      for(int it=-1; it<18; ++it){
        int is = it+1;
        if(is < 18){
          u16* b = smem + (is&1)*9216;
          const u16* A; const u16* W; int ld, k0;
          if(is < 2){ A = p.zb16 + (size_t)m0*128;  W = p.wih; ld = 128;  k0 = is*64; }
          else      { A = hbi    + (size_t)m0*1024; W = p.whh; ld = 1024; k0 = (is-2)*64; }
          *(u16x8*)(b + ar*LDS_STRIDE + ac) =
            *(const u16x8*)(A + (size_t)ar*ld + k0 + ac);
#pragma unroll
          for(int s=0; s<3; s++)
            *(u16x8*)(b + 2304 + s*2304 + ar*LDS_STRIDE + ac) =
              *(const u16x8*)(W + (size_t)(s*1024 + n0 + ar)*ld + k0 + ac);
        }
        if(it >= 0){
          u16* c = smem + (it&1)*9216;
          int ai3 = (it < 2) ? 2 : 3;
#pragma unroll
          for(int kc=0; kc<2; kc++){
            int ko = kc*32 + quad*8;
            bf16x8 a = ldfrag(c, wm*16 + l16, ko);
#pragma unroll
            for(int s=0; s<3; s++){
              int ai = (s==2) ? ai3 : s;
              bf16x8 bb = ldfrag(c + 2304 + s*2304, wn*16 + l16, ko);
              acc[ai] = mfma16(a, bb, acc[ai]);
            }
          }
        }
        __syncthreads();
      }
#pragma unroll
      for(int i=0; i<4; i++){
        int m = m0 + wm*16 + quad*4 + i;
        int n = n0 + wn*16 + l16;
        float r  = sigm (acc[0][i] + p.gbih[n]      + p.gbhh[n]);
        float z  = sigm (acc[1][i] + p.gbih[n+1024] + p.gbhh[n+1024]);
        float nn = tanhf(acc[2][i] + p.gbih[n+2048]
                         + r*(acc[3][i] + p.gbhh[n+2048]));
        float h  = hin[(size_t)m*1024 + n];
        float hv = (1.f-z)*nn + z*h;
        hout[(size_t)m*1024 + n] = hv;
        hbo [(size_t)m*1024 + n] = f2b(hv);
      }
    }
    gsync(p.bcnt, p.bgen);

    // ========== P2: gate+prop hidden (2048 cols), 512 tiles 32m x 64n ======
    {
      const int m0 = (blk & 15) * 32;
      const int n0 = (blk >> 4) * 64;             // 0..1984
      const u16* W; const float* bias;
      if(n0 < 1024){ W = p.tgw + (size_t)n0*1024;        bias = p.tgb + n0; }
      else         { W = p.tpw + (size_t)(n0-1024)*1024; bias = p.tpb + (n0-1024); }
      mlp_tile(hbo + (size_t)m0*1024, W, bias, 1,
               p.Hbuf + (size_t)m0*2176 + n0, smem, tid);
    }
    gsync(p.bcnt, p.bgen);

    // ========== P3: GP gemm (128 tiles 32x32) + loc tiles (32 x 32m64n) ====
    if(blk < 128){
      const int m0 = (blk >> 3) * 32, n0 = (blk & 7) * 32;
      const int reg1 = (n0 >= 128);
      const u16*  A = p.Hbuf + (size_t)m0*2176 + (reg1 ? 1024 : 0);
      const u16*  W = reg1 ? p.tphzw + (size_t)(n0-128)*1024
                           : p.tghzw + (size_t)n0*1024;
      const float* bias = reg1 ? p.tphzb + (n0-128) : p.tghzb + n0;
      f32x4 acc3 = {};
#pragma unroll 1
      for(int it=-1; it<16; ++it){
        int is = it+1;
        if(is < 16){
          u16* b = smem + (is&1)*4608;
          *(u16x8*)(b + ar*LDS_STRIDE + ac) =
            *(const u16x8*)(A + (size_t)ar*2176 + is*64 + ac);
          *(u16x8*)(b + 2304 + ar*LDS_STRIDE + ac) =
            *(const u16x8*)(W + (size_t)ar*1024 + is*64 + ac);
        }
        if(it >= 0){
          u16* c = smem + (it&1)*4608;
#pragma unroll
          for(int kc=0; kc<2; kc++){
            int ko = kc*32 + quad*8;
            acc3 = mfma16(ldfrag(c, wm*16 + l16, ko),
                          ldfrag(c + 2304, wn*16 + l16, ko), acc3);
          }
        }
        __syncthreads();
      }
#pragma unroll
      for(int i=0; i<4; i++){
        int m  = m0 + wm*16 + quad*4 + i;
        int cl = wn*16 + l16;
        p.GP[(size_t)m*256 + n0 + cl] = acc3[i] + bias[cl];
      }
    } else if(blk < 160){
      const int idx = blk - 128;
      const int m0  = (idx & 15) * 32;
      const int n0l = 2048 + (idx >> 4) * 64;
      mlp_tile(hbo + (size_t)m0*1024, p.tlw + (size_t)(n0l-2048)*1024,
               p.tlb + (n0l-2048), 0,
               p.Hbuf + (size_t)m0*2176 + n0l, smem, tid);
    }
    gsync(p.bcnt, p.bgen);

    // ========== P4: z_t scale GEMM (K=128) + reparam, 64 tiles 16m x 64n ===
    if(blk < 64){
      const int m0 = (blk >> 1) * 16, n0 = (blk & 1) * 64;
      u16* lp = smem;                           // 16 x 136
      {
        int r = tid >> 4, c = (tid & 15) * 8;
        const float* src = p.GP + (size_t)(m0+r)*256 + 128 + c;
        f32x4 p0 = *(const f32x4*)src, p1 = *(const f32x4*)(src+4);
        u16x8 o;
        o[0]=f2b(fmaxf(p0[0],0.f)); o[1]=f2b(fmaxf(p0[1],0.f));
        o[2]=f2b(fmaxf(p0[2],0.f)); o[3]=f2b(fmaxf(p0[3],0.f));
        o[4]=f2b(fmaxf(p1[0],0.f)); o[5]=f2b(fmaxf(p1[1],0.f));
        o[6]=f2b(fmaxf(p1[2],0.f)); o[7]=f2b(fmaxf(p1[3],0.f));
        *(u16x8*)(lp + r*136 + c) = o;
      }
      __syncthreads();
      f32x4 acc4 = {};
      const int col = n0 + w*16 + l16;
#pragma unroll
      for(int kc=0; kc<4; kc++){
        int ko = kc*32 + quad*8;
        acc4 = mfma16(ldfragS(lp, l16, ko, 136),
                      ldw8b(p.tsw + (size_t)col*128 + ko), acc4);
      }
#pragma unroll
      for(int i=0; i<4; i++){
        int gm = m0 + quad*4 + i;
        float zs  = softp(acc4[i] + p.tsb[col]);
        float g   = sigm(p.GP[(size_t)gm*256 + col]);
        float pv  = p.GP[(size_t)gm*256 + 128 + col];
        float loc = b2f(p.Hbuf[(size_t)gm*2176 + 2048 + col]);
        float zl  = (1.f-g)*loc + g*pv;
        float e   = p.eps[(size_t)gm*32768 + (size_t)t*128 + col];
        float zv  = zl + zs*e;
        p.out [(size_t)gm*32768 + (size_t)t*128 + col] = zv;
        p.zb16[(size_t)gm*128 + col] = f2b(zv);
      }
    }
    gsync(p.bcnt, p.bgen);
  }
}

// ------------------- FUSED obs branch: one block = 32 rows ------------------
// grid 4096. Reads z (fp32) from out[b,t,0:128], overwrites with x_loc|x_scale.
#define LH_S 520
__global__ __launch_bounds__(256) void k_obs(
  const u16* __restrict__ ogw,   const float* __restrict__ ogb,
  const u16* __restrict__ oghzw, const float* __restrict__ oghzb,
  const u16* __restrict__ opw,   const float* __restrict__ opb,
  const u16* __restrict__ ophzw, const float* __restrict__ ophzb,
  const u16* __restrict__ olw,   const float* __restrict__ olb,
  const u16* __restrict__ osw,   const float* __restrict__ osb,
  float* __restrict__ out)
{
  __shared__ u16 lz[32*136];
  __shared__ u16 lh[32*LH_S];
  __shared__ u16 lp[32*72];
  const int r0 = blockIdx.x*32;
  const int t  = r0 >> 9, b0 = r0 & 511;        // 32 | 512 -> single t per block
  const int tid = threadIdx.x;
  const int lane = tid & 63, w = tid>>6, l16 = lane&15, quad = lane>>4;

#pragma unroll
  for(int i=0;i<2;i++){
    int ch = tid + i*256;
    int r = ch>>4, c = (ch&15)*8;
    const float* src = out + (size_t)(b0+r)*32768 + (size_t)t*128 + c;
    f32x4 p0 = *(const f32x4*)src, p1 = *(const f32x4*)(src+4);
    u16x8 o;
    o[0]=f2b(p0[0]); o[1]=f2b(p0[1]); o[2]=f2b(p0[2]); o[3]=f2b(p0[3]);
    o[4]=f2b(p1[0]); o[5]=f2b(p1[1]); o[6]=f2b(p1[2]); o[7]=f2b(p1[3]);
    *(u16x8*)(lz + r*136 + c) = o;
  }
  __syncthreads();

  f32x4 accp[2] = {}, accg[2] = {};
  const int col = w*16 + l16;                   // this wave's output column

#pragma unroll 1
  for(int ph=0; ph<2; ph++){                    // 0 = prop path, 1 = gate path
    const u16* hw = ph ? ogw   : opw;
    const float* hb = ph ? ogb : opb;
    const u16* zw = ph ? oghzw : ophzw;
    f32x4* acc2    = ph ? accg : accp;
#pragma unroll 1
    for(int c2=0; c2<2; c2++){                  // hidden cols [c2*512, +512)
      __syncthreads();                          // protect lh from prior readers
      for(int nt = w; nt < 32; nt += 4){
        int n = c2*512 + nt*16 + l16;           // hidden unit = weight row
#pragma unroll
        for(int mi=0; mi<2; mi++){
          f32x4 a = {};
#pragma unroll
          for(int kc=0;kc<4;kc++){
            int ko = kc*32 + quad*8;
            a = mfma16(ldfragS(lz, mi*16+l16, ko, 136),
                       ldw8b(hw + (size_t)n*128 + ko), a);
          }
          float bias = hb[n];
#pragma unroll
          for(int i=0;i<4;i++)
            lh[(mi*16+quad*4+i)*LH_S + nt*16 + l16] = f2b(fmaxf(a[i]+bias, 0.f));
        }
      }
      __syncthreads();
#pragma unroll
      for(int mi=0;mi<2;mi++){
        f32x4 a = acc2[mi];
        for(int kc=0;kc<16;kc++){
          int ko = kc*32 + quad*8;
          a = mfma16(ldfragS(lh, mi*16+l16, ko, LH_S),
                     ldw8b(zw + (size_t)col*1024 + c2*512 + ko), a);
        }
        acc2[mi] = a;
      }
    }
    if(ph==0){
      float bias = ophzb[col];
#pragma unroll
      for(int mi=0;mi<2;mi++)
#pragma unroll
      for(int i=0;i<4;i++){
        float pv = accp[mi][i] + bias;          // proposed incl. bias
        accp[mi][i] = pv;
        lp[(mi*16+quad*4+i)*72 + col] = f2b(fmaxf(pv, 0.f));
      }
    }
  }

  f32x4 accl[2]={}, accs[2]={};
#pragma unroll
  for(int mi=0;mi<2;mi++){
#pragma unroll
    for(int kc=0;kc<4;kc++){
      int ko=kc*32+quad*8;
      accl[mi]=mfma16(ldfragS(lz,mi*16+l16,ko,136),
                      ldw8b(olw + (size_t)col*128 + ko), accl[mi]);
    }
#pragma unroll
    for(int kc=0;kc<2;kc++){
      int ko=kc*32+quad*8;
      accs[mi]=mfma16(ldfragS(lp,mi*16+l16,ko,72),
                      ldw8b(osw + (size_t)col*64 + ko), accs[mi]);
    }
  }
#pragma unroll
  for(int mi=0;mi<2;mi++)
#pragma unroll
  for(int i=0;i<4;i++){
    int r = mi*16 + quad*4 + i;
    float g  = sigm(accg[mi][i] + oghzb[col]);
    float pv = accp[mi][i];
    float lc = accl[mi][i] + olb[col];
    float xs = softp(accs[mi][i] + osb[col]);
    float xl = (1.f-g)*lc + g*pv;
    size_t o = (size_t)(b0+r)*32768 + (size_t)t*128 + col;
    out[o]      = xl;
    out[o + 64] = xs;
  }
}

// ---------------------------------------------------------------------------
extern "C" void kernel_launch(void* const* d_in, const int* in_sizes, int n_in,
                              void* d_out, int out_size, void* d_ws, size_t ws_size,
                              hipStream_t stream)
{
  (void)in_sizes; (void)n_in; (void)out_size; (void)ws_size;
  const float* eps   = (const float*)d_in[1];
  const float* z0    = (const float*)d_in[2];
  const float* h0    = (const float*)d_in[3];
  const float* gwih  = (const float*)d_in[4];  const float* gbih  = (const float*)d_in[5];
  const float* gwhh  = (const float*)d_in[6];  const float* gbhh  = (const float*)d_in[7];
  const float* tgw   = (const float*)d_in[8];  const float* tgb   = (const float*)d_in[9];
  const float* tghzw = (const float*)d_in[10]; const float* tghzb = (const float*)d_in[11];
  const float* tpw   = (const float*)d_in[12]; const float* tpb   = (const float*)d_in[13];
  const float* tphzw = (const float*)d_in[14]; const float* tphzb = (const float*)d_in[15];
  const float* tlw   = (const float*)d_in[16]; const float* tlb   = (const float*)d_in[17];
  const float* tsw   = (const float*)d_in[18]; const float* tsb   = (const float*)d_in[19];
  const float* ogw   = (const float*)d_in[20]; const float* ogb   = (const float*)d_in[21];
  const float* oghzw = (const float*)d_in[22]; const float* oghzb = (const float*)d_in[23];
  const float* opw   = (const float*)d_in[24]; const float* opb   = (const float*)d_in[25];
  const float* ophzw = (const float*)d_in[26]; const float* ophzb = (const float*)d_in[27];
  const float* olw   = (const float*)d_in[28]; const float* olb   = (const float*)d_in[29];
  const float* osw   = (const float*)d_in[30]; const float* osb   = (const float*)d_in[31];
  float* out = (float*)d_out;

  // ---- ws layout (~21.1 MB total) ----
  char* ws = (char*)d_ws;
  size_t off = 0;
  float* hbuf = (float*)(ws + off); off += (size_t)2*512*1024*4;   // 4.19 MB
  u16*   Hbuf = (u16*)  (ws + off); off += (size_t)512*2176*2;     // 2.23 MB
  float* GP   = (float*)(ws + off); off += (size_t)512*256*4;      // 0.52 MB
  u16*   hb16 = (u16*)  (ws + off); off += (size_t)2*512*1024*2;   // 2.10 MB
  u16*   zb16 = (u16*)  (ws + off); off += (size_t)512*128*2;      // 0.13 MB
  u16* wc_gwih  = (u16*)(ws + off); off += (size_t)3072*128 *2;
  u16* wc_gwhh  = (u16*)(ws + off); off += (size_t)3072*1024*2;
  u16* wc_tgw   = (u16*)(ws + off); off += (size_t)1024*1024*2;
  u16* wc_tpw   = (u16*)(ws + off); off += (size_t)1024*1024*2;
  u16* wc_tlw   = (u16*)(ws + off); off += (size_t)128*1024 *2;
  u16* wc_tghzw = (u16*)(ws + off); off += (size_t)128*1024 *2;
  u16* wc_tphzw = (u16*)(ws + off); off += (size_t)128*1024 *2;
  u16* wc_tsw   = (u16*)(ws + off); off += (size_t)128*128  *2;
  u16* wc_ogw   = (u16*)(ws + off); off += (size_t)1024*128 *2;
  u16* wc_opw   = (u16*)(ws + off); off += (size_t)1024*128 *2;
  u16* wc_oghzw = (u16*)(ws + off); off += (size_t)64*1024  *2;
  u16* wc_ophzw = (u16*)(ws + off); off += (size_t)64*1024  *2;
  u16* wc_olw   = (u16*)(ws + off); off += (size_t)64*128   *2;
  u16* wc_osw   = (u16*)(ws + off); off += (size_t)64*64    *2;
  unsigned* bar = (unsigned*)(ws + off); off += 256;               // barrier state

  // ---- one-time weight conversion (per call; inputs may be re-poisoned) ----
  #define CVT(src, dst, n) k_cvt<<<(n)/2048, 256, 0, stream>>>((src), (dst))
  CVT(gwih,  wc_gwih,  3072*128);
  CVT(gwhh,  wc_gwhh,  3072*1024);
  CVT(tgw,   wc_tgw,   1024*1024);
  CVT(tpw,   wc_tpw,   1024*1024);
  CVT(tlw,   wc_tlw,   128*1024);
  CVT(tghzw, wc_tghzw, 128*1024);
  CVT(tphzw, wc_tphzw, 128*1024);
  CVT(tsw,   wc_tsw,   128*128);
  CVT(ogw,   wc_ogw,   1024*128);
  CVT(opw,   wc_opw,   1024*128);
  CVT(oghzw, wc_oghzw, 64*1024);
  CVT(ophzw, wc_ophzw, 64*1024);
  CVT(olw,   wc_olw,   64*128);
  CVT(osw,   wc_osw,   64*64);
  #undef CVT
  k_bzero<<<1, 64, 0, stream>>>(bar);

  // ---- persistent recurrence (ordinary launch + software grid barrier) ----
  SeqP sp;
  sp.eps = eps; sp.h0 = h0; sp.z0 = z0;
  sp.gbih = gbih; sp.gbhh = gbhh;
  sp.tgb = tgb; sp.tpb = tpb; sp.tlb = tlb;
  sp.tghzb = tghzb; sp.tphzb = tphzb; sp.tsb = tsb;
  sp.wih = wc_gwih; sp.whh = wc_gwhh;
  sp.tgw = wc_tgw; sp.tpw = wc_tpw; sp.tlw = wc_tlw;
  sp.tghzw = wc_tghzw; sp.tphzw = wc_tphzw; sp.tsw = wc_tsw;
  sp.out = out; sp.hbuf = hbuf; sp.GP = GP;
  sp.Hbuf = Hbuf; sp.hb16 = hb16; sp.zb16 = zb16;
  sp.bcnt = bar; sp.bgen = bar + 32;
  k_seq<<<512, 256, 0, stream>>>(sp);

  // fused obs: reads z from out slices, overwrites them with x_loc|x_scale
  k_obs<<<4096, 256, 0, stream>>>(wc_ogw, ogb, wc_oghzw, oghzb,
                                  wc_opw, opb, wc_ophzw, ophzb,
                                  wc_olw, olb, wc_osw, osb, out);
}

// Round 4
// 13374.031 us; speedup vs baseline: 4.8202x; 1.9969x over previous
//
#include <hip/hip_runtime.h>
#include <math.h>

// ---------------------------------------------------------------------------
// StateSpaceModel: B=512 T=256 Z=128 X=64 R=1024 HT=HO=1024.
// R4: kill the L2-invalidate. R3's gsync used agent acquire/release fences
// (buffer_inv/buffer_wbl2) 4x/step -> full L2 flush -> 31.6 MB/step refetch
// (FETCH 8.1 GB), 102 us/step with MfmaUtil 2.4%. Now:
//  - NO fences. Cross-block buffers (hb16, zb16, Hbuf, GP) accessed with
//    relaxed AGENT-scope atomics (sc0 sc1: stores write through to the
//    coherence point, loads bypass L2) -> correct without invalidating.
//  - Weights: plain loads, L2-resident across all 256 steps. P2 tile map
//    swapped (n0 = blk&31) so blocks sharing weights land on one XCD
//    (round-robin %8) -> per-XCD weight footprint ~1.8 MB < 4 MB L2.
//  - Barrier: two-level monotonic tree (8 groups x 64 -> root), relaxed
//    atomics + compiler-only memory fences; __syncthreads provides the
//    vmcnt drain before signaling.
//  - h carried in REGISTERS (P1 block->tile map fixed over t, h is
//    block-private): fp32 hbuf deleted.
//  - accumulation order per output element unchanged -> same numerics.
// ---------------------------------------------------------------------------

typedef unsigned short u16;
typedef unsigned long long u64;
typedef __bf16 bf16x8 __attribute__((ext_vector_type(8)));
typedef u16    u16x8  __attribute__((ext_vector_type(8)));
typedef float  f32x4  __attribute__((ext_vector_type(4)));

#define DI __device__ __forceinline__
#define LDS_STRIDE 72   // 64 + 8 pad: 16B-aligned, 2-way bank alias (free)

DI u16  f2b(float f){ union{float f; unsigned u;} c; c.f = f;
                      return (u16)((c.u + 0x7fffu + ((c.u>>16)&1u))>>16); }  // RNE
DI float b2f(u16 x){ union{unsigned u; float f;} c; c.u = ((unsigned)x)<<16; return c.f; }
DI float sigm (float x){ return 1.f/(1.f+expf(-x)); }
DI float softp(float x){ return (x>15.f)? x : log1pf(expf(x)); }

DI f32x4 mfma16(bf16x8 a, bf16x8 b, f32x4 c){
  return __builtin_amdgcn_mfma_f32_16x16x32_bf16(a,b,c,0,0,0);
}
DI bf16x8 ldw8b(const u16* __restrict__ g){
  return __builtin_bit_cast(bf16x8, *(const u16x8*)g);
}
DI bf16x8 ldfragS(const u16* l, int row, int ko, int stride){
  return __builtin_bit_cast(bf16x8, *(const u16x8*)(l + row*stride + ko));
}
DI bf16x8 ldfrag(const u16* l, int row, int ko){ return ldfragS(l, row, ko, LDS_STRIDE); }

// ---- coherent (agent-scope, relaxed) access helpers: sc0 sc1, no fences ----
DI u64 ldc64(const void* p){
  return __hip_atomic_load((const u64*)p, __ATOMIC_RELAXED, __HIP_MEMORY_SCOPE_AGENT);
}
DI u16 ldc16(const u16* p){
  return __hip_atomic_load(p, __ATOMIC_RELAXED, __HIP_MEMORY_SCOPE_AGENT);
}
DI void stc16(u16* p, u16 v){
  __hip_atomic_store(p, v, __ATOMIC_RELAXED, __HIP_MEMORY_SCOPE_AGENT);
}
DI float ldc32f(const float* p){
  unsigned u = __hip_atomic_load((const unsigned*)p, __ATOMIC_RELAXED, __HIP_MEMORY_SCOPE_AGENT);
  union{unsigned u; float f;} c; c.u = u; return c.f;
}
DI void stc32f(float* p, float v){
  union{float f; unsigned u;} c; c.f = v;
  __hip_atomic_store((unsigned*)p, c.u, __ATOMIC_RELAXED, __HIP_MEMORY_SCOPE_AGENT);
}
// stage one 16B chunk (coherent) global -> LDS
DI void stage_cg(const u16* g, u16* l){
  u64 a = ldc64(g), b = ldc64(g + 4);
  *(u64*)l = a; *(u64*)(l + 4) = b;
}

// ---- two-level monotonic tree barrier (512 = 8 groups x 64), no fences ----
// bar layout (u32 words): grp counter at (blk&7)*32, root at 256, gen at 288.
DI void gsync(unsigned* bar, unsigned bi, int blk){
  __syncthreads();                         // drains vmcnt -> stores visible
  if(threadIdx.x == 0){
    unsigned v = __hip_atomic_fetch_add(bar + (blk & 7)*32, 1u,
                   __ATOMIC_RELAXED, __HIP_MEMORY_SCOPE_AGENT);
    if(v == bi*64u + 63u){
      unsigned r = __hip_atomic_fetch_add(bar + 256, 1u,
                     __ATOMIC_RELAXED, __HIP_MEMORY_SCOPE_AGENT);
      if(r == bi*8u + 7u)
        __hip_atomic_store(bar + 288, bi + 1u,
                           __ATOMIC_RELAXED, __HIP_MEMORY_SCOPE_AGENT);
    }
    while(__hip_atomic_load(bar + 288, __ATOMIC_RELAXED,
                            __HIP_MEMORY_SCOPE_AGENT) <= bi)
      __builtin_amdgcn_s_sleep(4);
  }
  asm volatile("" ::: "memory");           // compiler-only ordering
  __syncthreads();
}

// ---------------- one-time fp32 -> bf16 weight conversion -------------------
__global__ __launch_bounds__(256) void k_cvt(const float* __restrict__ s,
                                             u16* __restrict__ d){
  int i = (blockIdx.x*256 + threadIdx.x)*8;
  f32x4 p0 = *(const f32x4*)(s+i), p1 = *(const f32x4*)(s+i+4);
  u16x8 o;
  o[0]=f2b(p0[0]); o[1]=f2b(p0[1]); o[2]=f2b(p0[2]); o[3]=f2b(p0[3]);
  o[4]=f2b(p1[0]); o[5]=f2b(p1[1]); o[6]=f2b(p1[2]); o[7]=f2b(p1[3]);
  *(u16x8*)(d+i) = o;
}

// init hb16 buffer0 (h0 broadcast) + zb16 (z0 broadcast); plain stores are
// fine: kernel-boundary flush makes them visible to k_seq's coherent loads.
__global__ __launch_bounds__(256) void k_init(u16* __restrict__ hb,
                                              u16* __restrict__ zb,
                                              const float* __restrict__ h0,
                                              const float* __restrict__ z0){
  int idx = blockIdx.x*256 + threadIdx.x;           // 2048 blocks -> 524288
  hb[idx] = f2b(h0[idx & 1023]);
  if(idx < 512*128) zb[idx] = f2b(z0[idx & 127]);
}

__global__ void k_bzero(unsigned* b){ b[threadIdx.x] = 0u; b[threadIdx.x+256] = 0u; }

// ------------------------- persistent sequential kernel ---------------------
struct SeqP {
  const float *eps, *h0, *z0;
  const float *gbih, *gbhh, *tgb, *tpb, *tlb, *tghzb, *tphzb, *tsb;
  const u16 *wih, *whh, *tgw, *tpw, *tlw, *tghzw, *tphzw, *tsw;
  float *out, *GP;
  u16 *Hbuf, *hb16, *zb16;
  unsigned *bar;
};

// 32m x 64n x K=1024 tile: C = act(A @ W^T + b); dbuf; smem needs 2x6912 u16
// A is a cross-block activation buffer -> coherent staging loads.
DI void mlp_tile(const u16* __restrict__ A,      // + m0*1024 applied by caller
                 const u16* __restrict__ W,      // 64 region rows x 1024
                 const float* __restrict__ bias, int act,
                 u16* __restrict__ Cb,           // Hbuf + m0*2176 + n0
                 u16* smem, int tid)
{
  const int lane=tid&63, w=tid>>6, l16=lane&15, quad=lane>>4, wm=w>>1, wn=w&1;
  const int ar=tid>>3, ac=(tid&7)*8, br=tid>>2, bc=(tid&3)*16;
  f32x4 acc[2] = {};
#pragma unroll 1
  for(int it=-1; it<16; ++it){
    int is = it+1;
    if(is < 16){
      u16* b = smem + (is&1)*6912;
      stage_cg(A + (size_t)ar*1024 + is*64 + ac, b + ar*LDS_STRIDE + ac);
      u16* lb = b + 2304;
      *(u16x8*)(lb + br*LDS_STRIDE + bc) =
        *(const u16x8*)(W + (size_t)br*1024 + is*64 + bc);
      *(u16x8*)(lb + br*LDS_STRIDE + bc + 8) =
        *(const u16x8*)(W + (size_t)br*1024 + is*64 + bc + 8);
    }
    if(it >= 0){
      u16* c = smem + (it&1)*6912;
#pragma unroll
      for(int kc=0;kc<2;kc++){
        int ko = kc*32 + quad*8;
        bf16x8 a  = ldfrag(c, wm*16 + l16, ko);
        bf16x8 b0 = ldfrag(c + 2304, wn*32 + l16, ko);
        bf16x8 b1 = ldfrag(c + 2304, wn*32 + 16 + l16, ko);
        acc[0] = mfma16(a, b0, acc[0]);
        acc[1] = mfma16(a, b1, acc[1]);
      }
    }
    __syncthreads();
  }
#pragma unroll
  for(int nf=0; nf<2; nf++)
#pragma unroll
  for(int i=0; i<4; i++){
    int m  = wm*16 + quad*4 + i;
    int cl = wn*32 + nf*16 + l16;
    float v = acc[nf][i] + bias[cl];
    if(act) v = fmaxf(v, 0.f);
    stc16(&Cb[(size_t)m*2176 + cl], f2b(v));
  }
}

__global__ __launch_bounds__(256, 2) void k_seq(SeqP p)
{
  __shared__ u16 smem[18432];                   // 36.9 KB (2 dbuf x 9216)
  const int blk  = blockIdx.x;                  // 0..511
  const int tid  = threadIdx.x;
  const int lane = tid & 63, w = tid >> 6;
  const int l16  = lane & 15, quad = lane >> 4;
  const int wm   = w >> 1, wn = w & 1;
  const int ar   = tid >> 3, ac = (tid & 7) * 8;   // 32-row tile staging

  // P1 fixed tile mapping (same every step) -> h lives in registers
  const int p1m0 = (blk >> 5) * 32;
  const int p1n0 = (blk & 31) * 32;
  const int p1n  = p1n0 + wn*16 + l16;
  f32x4 hreg;
  { float h0v = p.h0[p1n]; hreg[0]=h0v; hreg[1]=h0v; hreg[2]=h0v; hreg[3]=h0v; }

  unsigned bi = 0;

#pragma unroll 1
  for(int t = 0; t < 256; t++){
    const u16* hbi = p.hb16 + (size_t)(t&1)*524288;
    u16*       hbo = p.hb16 + (size_t)((t+1)&1)*524288;

    // ========== P1: GRU, 512 tiles 32m x 32n x 3 gates, 18 iters dbuf ======
    {
      f32x4 acc[4] = {};              // 0=r, 1=z, 2=i_n, 3=h_n
#pragma unroll 1
      for(int it=-1; it<18; ++it){
        int is = it+1;
        if(is < 18){
          u16* b = smem + (is&1)*9216;
          const u16* A; const u16* W; int ld, k0;
          if(is < 2){ A = p.zb16 + (size_t)p1m0*128;  W = p.wih; ld = 128;  k0 = is*64; }
          else      { A = hbi    + (size_t)p1m0*1024; W = p.whh; ld = 1024; k0 = (is-2)*64; }
          stage_cg(A + (size_t)ar*ld + k0 + ac, b + ar*LDS_STRIDE + ac);
#pragma unroll
          for(int s=0; s<3; s++)
            *(u16x8*)(b + 2304 + s*2304 + ar*LDS_STRIDE + ac) =
              *(const u16x8*)(W + (size_t)(s*1024 + p1n0 + ar)*ld + k0 + ac);
        }
        if(it >= 0){
          u16* c = smem + (it&1)*9216;
          int ai3 = (it < 2) ? 2 : 3;
#pragma unroll
          for(int kc=0; kc<2; kc++){
            int ko = kc*32 + quad*8;
            bf16x8 a = ldfrag(c, wm*16 + l16, ko);
#pragma unroll
            for(int s=0; s<3; s++){
              int ai = (s==2) ? ai3 : s;
              bf16x8 bb = ldfrag(c + 2304 + s*2304, wn*16 + l16, ko);
              acc[ai] = mfma16(a, bb, acc[ai]);
            }
          }
        }
        __syncthreads();
      }
#pragma unroll
      for(int i=0; i<4; i++){
        int m = p1m0 + wm*16 + quad*4 + i;
        int n = p1n;
        float r  = sigm (acc[0][i] + p.gbih[n]      + p.gbhh[n]);
        float z  = sigm (acc[1][i] + p.gbih[n+1024] + p.gbhh[n+1024]);
        float nn = tanhf(acc[2][i] + p.gbih[n+2048]
                         + r*(acc[3][i] + p.gbhh[n+2048]));
        float hv = (1.f-z)*nn + z*hreg[i];
        hreg[i] = hv;
        stc16(&hbo[(size_t)m*1024 + n], f2b(hv));
      }
    }
    gsync(p.bar, bi++, blk);

    // ========== P2: gate+prop hidden (2048 cols), 512 tiles 32m x 64n ======
    // n0 = blk&31 so the 16 blocks sharing a weight panel sit on one XCD.
    {
      const int m0 = (blk >> 5) * 32;
      const int n0 = (blk & 31) * 64;             // 0..1984
      const u16* W; const float* bias;
      if(n0 < 1024){ W = p.tgw + (size_t)n0*1024;        bias = p.tgb + n0; }
      else         { W = p.tpw + (size_t)(n0-1024)*1024; bias = p.tpb + (n0-1024); }
      mlp_tile(hbo + (size_t)m0*1024, W, bias, 1,
               p.Hbuf + (size_t)m0*2176 + n0, smem, tid);
    }
    gsync(p.bar, bi++, blk);

    // ========== P3: GP gemm (128 tiles 32x32) + loc tiles (32 x 32m64n) ====
    if(blk < 128){
      const int m0 = (blk >> 3) * 32, n0 = (blk & 7) * 32;
      const int reg1 = (n0 >= 128);
      const u16*  A = p.Hbuf + (size_t)m0*2176 + (reg1 ? 1024 : 0);
      const u16*  W = reg1 ? p.tphzw + (size_t)(n0-128)*1024
                           : p.tghzw + (size_t)n0*1024;
      const float* bias = reg1 ? p.tphzb + (n0-128) : p.tghzb + n0;
      f32x4 acc3 = {};
#pragma unroll 1
      for(int it=-1; it<16; ++it){
        int is = it+1;
        if(is < 16){
          u16* b = smem + (is&1)*4608;
          stage_cg(A + (size_t)ar*2176 + is*64 + ac, b + ar*LDS_STRIDE + ac);
          *(u16x8*)(b + 2304 + ar*LDS_STRIDE + ac) =
            *(const u16x8*)(W + (size_t)ar*1024 + is*64 + ac);
        }
        if(it >= 0){
          u16* c = smem + (it&1)*4608;
#pragma unroll
          for(int kc=0; kc<2; kc++){
            int ko = kc*32 + quad*8;
            acc3 = mfma16(ldfrag(c, wm*16 + l16, ko),
                          ldfrag(c + 2304, wn*16 + l16, ko), acc3);
          }
        }
        __syncthreads();
      }
#pragma unroll
      for(int i=0; i<4; i++){
        int m  = m0 + wm*16 + quad*4 + i;
        int cl = wn*16 + l16;
        stc32f(&p.GP[(size_t)m*256 + n0 + cl], acc3[i] + bias[cl]);
      }
    } else if(blk < 160){
      const int idx = blk - 128;
      const int m0  = (idx & 15) * 32;
      const int n0l = 2048 + (idx >> 4) * 64;
      mlp_tile(hbo + (size_t)m0*1024, p.tlw + (size_t)(n0l-2048)*1024,
               p.tlb + (n0l-2048), 0,
               p.Hbuf + (size_t)m0*2176 + n0l, smem, tid);
    }
    gsync(p.bar, bi++, blk);

    // ========== P4: z_t scale GEMM (K=128) + reparam, 64 tiles 16m x 64n ===
    if(blk < 64){
      const int m0 = (blk >> 1) * 16, n0 = (blk & 1) * 64;
      u16* lp = smem;                           // 16 x 136
      {
        int r = tid >> 4, c = (tid & 15) * 8;
        const float* src = p.GP + (size_t)(m0+r)*256 + 128 + c;
        union{u64 q; float f[2];} q0,q1,q2,q3;
        q0.q = ldc64(src);   q1.q = ldc64(src+2);
        q2.q = ldc64(src+4); q3.q = ldc64(src+6);
        u16x8 o;
        o[0]=f2b(fmaxf(q0.f[0],0.f)); o[1]=f2b(fmaxf(q0.f[1],0.f));
        o[2]=f2b(fmaxf(q1.f[0],0.f)); o[3]=f2b(fmaxf(q1.f[1],0.f));
        o[4]=f2b(fmaxf(q2.f[0],0.f)); o[5]=f2b(fmaxf(q2.f[1],0.f));
        o[6]=f2b(fmaxf(q3.f[0],0.f)); o[7]=f2b(fmaxf(q3.f[1],0.f));
        *(u16x8*)(lp + r*136 + c) = o;
      }
      __syncthreads();
      f32x4 acc4 = {};
      const int col = n0 + w*16 + l16;
#pragma unroll
      for(int kc=0; kc<4; kc++){
        int ko = kc*32 + quad*8;
        acc4 = mfma16(ldfragS(lp, l16, ko, 136),
                      ldw8b(p.tsw + (size_t)col*128 + ko), acc4);
      }
#pragma unroll
      for(int i=0; i<4; i++){
        int gm = m0 + quad*4 + i;
        float zs  = softp(acc4[i] + p.tsb[col]);
        float g   = sigm(ldc32f(&p.GP[(size_t)gm*256 + col]));
        float pv  = ldc32f(&p.GP[(size_t)gm*256 + 128 + col]);
        float loc = b2f(ldc16(&p.Hbuf[(size_t)gm*2176 + 2048 + col]));
        float zl  = (1.f-g)*loc + g*pv;
        float e   = p.eps[(size_t)gm*32768 + (size_t)t*128 + col];
        float zv  = zl + zs*e;
        p.out[(size_t)gm*32768 + (size_t)t*128 + col] = zv;   // plain: next
        stc16(&p.zb16[(size_t)gm*128 + col], f2b(zv));        // kernel reads out
      }
    }
    gsync(p.bar, bi++, blk);
  }
}

// ------------------- FUSED obs branch: one block = 32 rows ------------------
// grid 4096. Reads z (fp32) from out[b,t,0:128], overwrites with x_loc|x_scale.
#define LH_S 520
__global__ __launch_bounds__(256) void k_obs(
  const u16* __restrict__ ogw,   const float* __restrict__ ogb,
  const u16* __restrict__ oghzw, const float* __restrict__ oghzb,
  const u16* __restrict__ opw,   const float* __restrict__ opb,
  const u16* __restrict__ ophzw, const float* __restrict__ ophzb,
  const u16* __restrict__ olw,   const float* __restrict__ olb,
  const u16* __restrict__ osw,   const float* __restrict__ osb,
  float* __restrict__ out)
{
  __shared__ u16 lz[32*136];
  __shared__ u16 lh[32*LH_S];
  __shared__ u16 lp[32*72];
  const int r0 = blockIdx.x*32;
  const int t  = r0 >> 9, b0 = r0 & 511;        // 32 | 512 -> single t per block
  const int tid = threadIdx.x;
  const int lane = tid & 63, w = tid>>6, l16 = lane&15, quad = lane>>4;

#pragma unroll
  for(int i=0;i<2;i++){
    int ch = tid + i*256;
    int r = ch>>4, c = (ch&15)*8;
    const float* src = out + (size_t)(b0+r)*32768 + (size_t)t*128 + c;
    f32x4 p0 = *(const f32x4*)src, p1 = *(const f32x4*)(src+4);
    u16x8 o;
    o[0]=f2b(p0[0]); o[1]=f2b(p0[1]); o[2]=f2b(p0[2]); o[3]=f2b(p0[3]);
    o[4]=f2b(p1[0]); o[5]=f2b(p1[1]); o[6]=f2b(p1[2]); o[7]=f2b(p1[3]);
    *(u16x8*)(lz + r*136 + c) = o;
  }
  __syncthreads();

  f32x4 accp[2] = {}, accg[2] = {};
  const int col = w*16 + l16;                   // this wave's output column

#pragma unroll 1
  for(int ph=0; ph<2; ph++){                    // 0 = prop path, 1 = gate path
    const u16* hw = ph ? ogw   : opw;
    const float* hb = ph ? ogb : opb;
    const u16* zw = ph ? oghzw : ophzw;
    f32x4* acc2    = ph ? accg : accp;
#pragma unroll 1
    for(int c2=0; c2<2; c2++){                  // hidden cols [c2*512, +512)
      __syncthreads();                          // protect lh from prior readers
      for(int nt = w; nt < 32; nt += 4){
        int n = c2*512 + nt*16 + l16;           // hidden unit = weight row
#pragma unroll
        for(int mi=0; mi<2; mi++){
          f32x4 a = {};
#pragma unroll
          for(int kc=0;kc<4;kc++){
            int ko = kc*32 + quad*8;
            a = mfma16(ldfragS(lz, mi*16+l16, ko, 136),
                       ldw8b(hw + (size_t)n*128 + ko), a);
          }
          float bias = hb[n];
#pragma unroll
          for(int i=0;i<4;i++)
            lh[(mi*16+quad*4+i)*LH_S + nt*16 + l16] = f2b(fmaxf(a[i]+bias, 0.f));
        }
      }
      __syncthreads();
#pragma unroll
      for(int mi=0;mi<2;mi++){
        f32x4 a = acc2[mi];
        for(int kc=0;kc<16;kc++){
          int ko = kc*32 + quad*8;
          a = mfma16(ldfragS(lh, mi*16+l16, ko, LH_S),
                     ldw8b(zw + (size_t)col*1024 + c2*512 + ko), a);
        }
        acc2[mi] = a;
      }
    }
    if(ph==0){
      float bias = ophzb[col];
#pragma unroll
      for(int mi=0;mi<2;mi++)
#pragma unroll
      for(int i=0;i<4;i++){
        float pv = accp[mi][i] + bias;          // proposed incl. bias
        accp[mi][i] = pv;
        lp[(mi*16+quad*4+i)*72 + col] = f2b(fmaxf(pv, 0.f));
      }
    }
  }

  f32x4 accl[2]={}, accs[2]={};
#pragma unroll
  for(int mi=0;mi<2;mi++){
#pragma unroll
    for(int kc=0;kc<4;kc++){
      int ko=kc*32+quad*8;
      accl[mi]=mfma16(ldfragS(lz,mi*16+l16,ko,136),
                      ldw8b(olw + (size_t)col*128 + ko), accl[mi]);
    }
#pragma unroll
    for(int kc=0;kc<2;kc++){
      int ko=kc*32+quad*8;
      accs[mi]=mfma16(ldfragS(lp,mi*16+l16,ko,72),
                      ldw8b(osw + (size_t)col*64 + ko), accs[mi]);
    }
  }
#pragma unroll
  for(int mi=0;mi<2;mi++)
#pragma unroll
  for(int i=0;i<4;i++){
    int r = mi*16 + quad*4 + i;
    float g  = sigm(accg[mi][i] + oghzb[col]);
    float pv = accp[mi][i];
    float lc = accl[mi][i] + olb[col];
    float xs = softp(accs[mi][i] + osb[col]);
    float xl = (1.f-g)*lc + g*pv;
    size_t o = (size_t)(b0+r)*32768 + (size_t)t*128 + col;
    out[o]      = xl;
    out[o + 64] = xs;
  }
}

// ---------------------------------------------------------------------------
extern "C" void kernel_launch(void* const* d_in, const int* in_sizes, int n_in,
                              void* d_out, int out_size, void* d_ws, size_t ws_size,
                              hipStream_t stream)
{
  (void)in_sizes; (void)n_in; (void)out_size; (void)ws_size;
  const float* eps   = (const float*)d_in[1];
  const float* z0    = (const float*)d_in[2];
  const float* h0    = (const float*)d_in[3];
  const float* gwih  = (const float*)d_in[4];  const float* gbih  = (const float*)d_in[5];
  const float* gwhh  = (const float*)d_in[6];  const float* gbhh  = (const float*)d_in[7];
  const float* tgw   = (const float*)d_in[8];  const float* tgb   = (const float*)d_in[9];
  const float* tghzw = (const float*)d_in[10]; const float* tghzb = (const float*)d_in[11];
  const float* tpw   = (const float*)d_in[12]; const float* tpb   = (const float*)d_in[13];
  const float* tphzw = (const float*)d_in[14]; const float* tphzb = (const float*)d_in[15];
  const float* tlw   = (const float*)d_in[16]; const float* tlb   = (const float*)d_in[17];
  const float* tsw   = (const float*)d_in[18]; const float* tsb   = (const float*)d_in[19];
  const float* ogw   = (const float*)d_in[20]; const float* ogb   = (const float*)d_in[21];
  const float* oghzw = (const float*)d_in[22]; const float* oghzb = (const float*)d_in[23];
  const float* opw   = (const float*)d_in[24]; const float* opb   = (const float*)d_in[25];
  const float* ophzw = (const float*)d_in[26]; const float* ophzb = (const float*)d_in[27];
  const float* olw   = (const float*)d_in[28]; const float* olb   = (const float*)d_in[29];
  const float* osw   = (const float*)d_in[30]; const float* osb   = (const float*)d_in[31];
  float* out = (float*)d_out;

  // ---- ws layout (~17.9 MB total) ----
  char* ws = (char*)d_ws;
  size_t off = 0;
  u16*   Hbuf = (u16*)  (ws + off); off += (size_t)512*2176*2;     // 2.23 MB
  float* GP   = (float*)(ws + off); off += (size_t)512*256*4;      // 0.52 MB
  u16*   hb16 = (u16*)  (ws + off); off += (size_t)2*512*1024*2;   // 2.10 MB
  u16*   zb16 = (u16*)  (ws + off); off += (size_t)512*128*2;      // 0.13 MB
  u16* wc_gwih  = (u16*)(ws + off); off += (size_t)3072*128 *2;
  u16* wc_gwhh  = (u16*)(ws + off); off += (size_t)3072*1024*2;
  u16* wc_tgw   = (u16*)(ws + off); off += (size_t)1024*1024*2;
  u16* wc_tpw   = (u16*)(ws + off); off += (size_t)1024*1024*2;
  u16* wc_tlw   = (u16*)(ws + off); off += (size_t)128*1024 *2;
  u16* wc_tghzw = (u16*)(ws + off); off += (size_t)128*1024 *2;
  u16* wc_tphzw = (u16*)(ws + off); off += (size_t)128*1024 *2;
  u16* wc_tsw   = (u16*)(ws + off); off += (size_t)128*128  *2;
  u16* wc_ogw   = (u16*)(ws + off); off += (size_t)1024*128 *2;
  u16* wc_opw   = (u16*)(ws + off); off += (size_t)1024*128 *2;
  u16* wc_oghzw = (u16*)(ws + off); off += (size_t)64*1024  *2;
  u16* wc_ophzw = (u16*)(ws + off); off += (size_t)64*1024  *2;
  u16* wc_olw   = (u16*)(ws + off); off += (size_t)64*128   *2;
  u16* wc_osw   = (u16*)(ws + off); off += (size_t)64*64    *2;
  unsigned* bar = (unsigned*)(ws + off); off += 2048;              // barrier

  // ---- one-time weight conversion (per call; inputs may be re-poisoned) ----
  #define CVT(src, dst, n) k_cvt<<<(n)/2048, 256, 0, stream>>>((src), (dst))
  CVT(gwih,  wc_gwih,  3072*128);
  CVT(gwhh,  wc_gwhh,  3072*1024);
  CVT(tgw,   wc_tgw,   1024*1024);
  CVT(tpw,   wc_tpw,   1024*1024);
  CVT(tlw,   wc_tlw,   128*1024);
  CVT(tghzw, wc_tghzw, 128*1024);
  CVT(tphzw, wc_tphzw, 128*1024);
  CVT(tsw,   wc_tsw,   128*128);
  CVT(ogw,   wc_ogw,   1024*128);
  CVT(opw,   wc_opw,   1024*128);
  CVT(oghzw, wc_oghzw, 64*1024);
  CVT(ophzw, wc_ophzw, 64*1024);
  CVT(olw,   wc_olw,   64*128);
  CVT(osw,   wc_osw,   64*64);
  #undef CVT
  k_init <<<2048, 256, 0, stream>>>(hb16, zb16, h0, z0);
  k_bzero<<<1, 256, 0, stream>>>(bar);

  // ---- persistent recurrence (ordinary launch + software tree barrier) ----
  SeqP sp;
  sp.eps = eps; sp.h0 = h0; sp.z0 = z0;
  sp.gbih = gbih; sp.gbhh = gbhh;
  sp.tgb = tgb; sp.tpb = tpb; sp.tlb = tlb;
  sp.tghzb = tghzb; sp.tphzb = tphzb; sp.tsb = tsb;
  sp.wih = wc_gwih; sp.whh = wc_gwhh;
  sp.tgw = wc_tgw; sp.tpw = wc_tpw; sp.tlw = wc_tlw;
  sp.tghzw = wc_tghzw; sp.tphzw = wc_tphzw; sp.tsw = wc_tsw;
  sp.out = out; sp.GP = GP;
  sp.Hbuf = Hbuf; sp.hb16 = hb16; sp.zb16 = zb16;
  sp.bar = bar;
  k_seq<<<512, 256, 0, stream>>>(sp);

  // fused obs: reads z from out slices, overwrites them with x_loc|x_scale
  k_obs<<<4096, 256, 0, stream>>>(wc_ogw, ogb, wc_oghzw, oghzb,
                                  wc_opw, opb, wc_ophzw, ophzb,
                                  wc_olw, olb, wc_osw, osb, out);
}

// Round 5
// 10771.564 us; speedup vs baseline: 5.9848x; 1.2416x over previous
//
#include <hip/hip_runtime.h>
#include <math.h>

// ---------------------------------------------------------------------------
// StateSpaceModel: B=512 T=256 Z=128 X=64 R=1024 HT=HO=1024.
// R5: hide the coherent-load latency. R4 profiled at MfmaUtil 4.9%,
// 51 us/step: every k-iter issued its staged loads and immediately consumed
// them (ds_write forces vmcnt wait) + __syncthreads drained vmcnt(0) ->
// ~900cy exposed per iter x ~51 iters/step. Now:
//  - register-prefetch software pipeline in all phase k-loops: depth 3 (P1)
//    / depth 4 (P2,P3), named register sets (no runtime indexing),
//    loads for iter i+d issued between barrier and compute of iter i.
//  - raw s_barrier + explicit "s_waitcnt lgkmcnt(0)" per iter (NOT
//    __syncthreads) -> prefetched global loads stay in flight across
//    barriers; compiler emits counted vmcnt waits at the ds_writes only.
//  - single barrier per iter (overwrite of LDS buf b at iter i+2 is fenced
//    by barrier i+1, which postdates all consumption at iter i).
//  - everything else (relaxed agent-scope coherent access, tree barrier,
//    h in registers, bf16 weight cache) unchanged from R4.
//  - accumulation order per output element unchanged -> same numerics.
// ---------------------------------------------------------------------------

typedef unsigned short u16;
typedef unsigned long long u64;
typedef __bf16 bf16x8 __attribute__((ext_vector_type(8)));
typedef u16    u16x8  __attribute__((ext_vector_type(8)));
typedef float  f32x4  __attribute__((ext_vector_type(4)));

#define DI __device__ __forceinline__
#define LDS_STRIDE 72   // 64 + 8 pad: 16B-aligned, 2-way bank alias (free)

DI u16  f2b(float f){ union{float f; unsigned u;} c; c.f = f;
                      return (u16)((c.u + 0x7fffu + ((c.u>>16)&1u))>>16); }  // RNE
DI float b2f(u16 x){ union{unsigned u; float f;} c; c.u = ((unsigned)x)<<16; return c.f; }
DI float sigm (float x){ return 1.f/(1.f+expf(-x)); }
DI float softp(float x){ return (x>15.f)? x : log1pf(expf(x)); }

DI f32x4 mfma16(bf16x8 a, bf16x8 b, f32x4 c){
  return __builtin_amdgcn_mfma_f32_16x16x32_bf16(a,b,c,0,0,0);
}
DI bf16x8 ldw8b(const u16* __restrict__ g){
  return __builtin_bit_cast(bf16x8, *(const u16x8*)g);
}
DI bf16x8 ldfragS(const u16* l, int row, int ko, int stride){
  return __builtin_bit_cast(bf16x8, *(const u16x8*)(l + row*stride + ko));
}
DI bf16x8 ldfrag(const u16* l, int row, int ko){ return ldfragS(l, row, ko, LDS_STRIDE); }

// ---- coherent (agent-scope, relaxed) access helpers: sc0 sc1, no fences ----
DI u64 ldc64(const void* p){
  return __hip_atomic_load((const u64*)p, __ATOMIC_RELAXED, __HIP_MEMORY_SCOPE_AGENT);
}
DI u16x8 ldc128(const u16* g){
  union{u64 q[2]; u16x8 v;} u; u.q[0] = ldc64(g); u.q[1] = ldc64(g + 4); return u.v;
}
DI u16 ldc16(const u16* p){
  return __hip_atomic_load(p, __ATOMIC_RELAXED, __HIP_MEMORY_SCOPE_AGENT);
}
DI void stc16(u16* p, u16 v){
  __hip_atomic_store(p, v, __ATOMIC_RELAXED, __HIP_MEMORY_SCOPE_AGENT);
}
DI float ldc32f(const float* p){
  unsigned u = __hip_atomic_load((const unsigned*)p, __ATOMIC_RELAXED, __HIP_MEMORY_SCOPE_AGENT);
  union{unsigned u; float f;} c; c.u = u; return c.f;
}
DI void stc32f(float* p, float v){
  union{float f; unsigned u;} c; c.f = v;
  __hip_atomic_store((unsigned*)p, c.u, __ATOMIC_RELAXED, __HIP_MEMORY_SCOPE_AGENT);
}

// ---- two-level monotonic tree barrier (512 = 8 groups x 64), no fences ----
DI void gsync(unsigned* bar, unsigned bi, int blk){
  __syncthreads();                         // drains vmcnt -> stores visible
  if(threadIdx.x == 0){
    unsigned v = __hip_atomic_fetch_add(bar + (blk & 7)*32, 1u,
                   __ATOMIC_RELAXED, __HIP_MEMORY_SCOPE_AGENT);
    if(v == bi*64u + 63u){
      unsigned r = __hip_atomic_fetch_add(bar + 256, 1u,
                     __ATOMIC_RELAXED, __HIP_MEMORY_SCOPE_AGENT);
      if(r == bi*8u + 7u)
        __hip_atomic_store(bar + 288, bi + 1u,
                           __ATOMIC_RELAXED, __HIP_MEMORY_SCOPE_AGENT);
    }
    while(__hip_atomic_load(bar + 288, __ATOMIC_RELAXED,
                            __HIP_MEMORY_SCOPE_AGENT) <= bi)
      __builtin_amdgcn_s_sleep(4);
  }
  asm volatile("" ::: "memory");           // compiler-only ordering
  __syncthreads();
}

// ---------------- one-time fp32 -> bf16 weight conversion -------------------
__global__ __launch_bounds__(256) void k_cvt(const float* __restrict__ s,
                                             u16* __restrict__ d){
  int i = (blockIdx.x*256 + threadIdx.x)*8;
  f32x4 p0 = *(const f32x4*)(s+i), p1 = *(const f32x4*)(s+i+4);
  u16x8 o;
  o[0]=f2b(p0[0]); o[1]=f2b(p0[1]); o[2]=f2b(p0[2]); o[3]=f2b(p0[3]);
  o[4]=f2b(p1[0]); o[5]=f2b(p1[1]); o[6]=f2b(p1[2]); o[7]=f2b(p1[3]);
  *(u16x8*)(d+i) = o;
}

__global__ __launch_bounds__(256) void k_init(u16* __restrict__ hb,
                                              u16* __restrict__ zb,
                                              const float* __restrict__ h0,
                                              const float* __restrict__ z0){
  int idx = blockIdx.x*256 + threadIdx.x;           // 2048 blocks -> 524288
  hb[idx] = f2b(h0[idx & 1023]);
  if(idx < 512*128) zb[idx] = f2b(z0[idx & 127]);
}

__global__ void k_bzero(unsigned* b){ b[threadIdx.x] = 0u; b[threadIdx.x+256] = 0u; }

// ------------------------- persistent sequential kernel ---------------------
struct SeqP {
  const float *eps, *h0, *z0;
  const float *gbih, *gbhh, *tgb, *tpb, *tlb, *tghzb, *tphzb, *tsb;
  const u16 *wih, *whh, *tgw, *tpw, *tlw, *tghzw, *tphzw, *tsw;
  float *out, *GP;
  u16 *Hbuf, *hb16, *zb16;
  unsigned *bar;
};

// 32m x 64n x K=1024 tile: C = act(A @ W^T + b); depth-4 reg prefetch,
// raw s_barrier (1/iter), LDS dbuf 2x6912 u16.
DI void mlp_tile(const u16* __restrict__ A,      // + m0*1024 applied by caller
                 const u16* __restrict__ W,      // 64 region rows x 1024
                 const float* __restrict__ bias, int act,
                 u16* __restrict__ Cb,           // Hbuf + m0*2176 + n0
                 u16* smem, int tid)
{
  const int lane=tid&63, w=tid>>6, l16=lane&15, quad=lane>>4, wm=w>>1, wn=w&1;
  const int ar=tid>>3, ac=(tid&7)*8, br=tid>>2, bc=(tid&3)*16;
  f32x4 acc[2] = {};
  u16x8 a0,a1,a2,a3,u0,u1,u2,u3,v0,v1,v2,v3;
#define MT_ISSUE(ra,ru,rv,is) do{ \
    ra = ldc128(A + (size_t)ar*1024 + (is)*64 + ac); \
    ru = *(const u16x8*)(W + (size_t)br*1024 + (is)*64 + bc); \
    rv = *(const u16x8*)(W + (size_t)br*1024 + (is)*64 + bc + 8); \
  }while(0)
#define MT_STEP(ra,ru,rv,it,nx) do{ \
    u16* b_ = smem + ((it)&1)*6912; \
    *(u16x8*)(b_ + ar*LDS_STRIDE + ac) = ra; \
    *(u16x8*)(b_ + 2304 + br*LDS_STRIDE + bc) = ru; \
    *(u16x8*)(b_ + 2304 + br*LDS_STRIDE + bc + 8) = rv; \
    asm volatile("s_waitcnt lgkmcnt(0)" ::: "memory"); \
    __builtin_amdgcn_s_barrier(); \
    __builtin_amdgcn_sched_barrier(0); \
    if((nx) < 16) MT_ISSUE(ra,ru,rv,(nx)); \
    _Pragma("unroll") \
    for(int kc=0;kc<2;kc++){ \
      int ko = kc*32 + quad*8; \
      bf16x8 aa = ldfrag(b_, wm*16 + l16, ko); \
      bf16x8 q0 = ldfrag(b_ + 2304, wn*32 + l16, ko); \
      bf16x8 q1 = ldfrag(b_ + 2304, wn*32 + 16 + l16, ko); \
      acc[0] = mfma16(aa,q0,acc[0]); \
      acc[1] = mfma16(aa,q1,acc[1]); \
    } \
  }while(0)
  MT_ISSUE(a0,u0,v0,0); MT_ISSUE(a1,u1,v1,1);
  MT_ISSUE(a2,u2,v2,2); MT_ISSUE(a3,u3,v3,3);
#pragma unroll 1
  for(int ib=0; ib<16; ib+=4){
    MT_STEP(a0,u0,v0, ib+0, ib+4);
    MT_STEP(a1,u1,v1, ib+1, ib+5);
    MT_STEP(a2,u2,v2, ib+2, ib+6);
    MT_STEP(a3,u3,v3, ib+3, ib+7);
  }
#undef MT_ISSUE
#undef MT_STEP
  __syncthreads();
#pragma unroll
  for(int nf=0; nf<2; nf++)
#pragma unroll
  for(int i=0; i<4; i++){
    int m  = wm*16 + quad*4 + i;
    int cl = wn*32 + nf*16 + l16;
    float v = acc[nf][i] + bias[cl];
    if(act) v = fmaxf(v, 0.f);
    stc16(&Cb[(size_t)m*2176 + cl], f2b(v));
  }
}

__global__ __launch_bounds__(256, 2) void k_seq(SeqP p)
{
  __shared__ u16 smem[18432];                   // 36.9 KB (2 dbuf x 9216)
  const int blk  = blockIdx.x;                  // 0..511
  const int tid  = threadIdx.x;
  const int lane = tid & 63, w = tid >> 6;
  const int l16  = lane & 15, quad = lane >> 4;
  const int wm   = w >> 1, wn = w & 1;
  const int ar   = tid >> 3, ac = (tid & 7) * 8;   // 32-row tile staging

  // P1 fixed tile mapping (same every step) -> h lives in registers
  const int p1m0 = (blk >> 5) * 32;
  const int p1n0 = (blk & 31) * 32;
  const int p1n  = p1n0 + wn*16 + l16;
  f32x4 hreg;
  { float h0v = p.h0[p1n]; hreg[0]=h0v; hreg[1]=h0v; hreg[2]=h0v; hreg[3]=h0v; }

  unsigned bi = 0;

#pragma unroll 1
  for(int t = 0; t < 256; t++){
    const u16* hbi = p.hb16 + (size_t)(t&1)*524288;
    u16*       hbo = p.hb16 + (size_t)((t+1)&1)*524288;

    // ========== P1: GRU, 512 tiles 32m x 32n x 3 gates, 18 iters, depth 3 ==
    {
      f32x4 acc[4] = {};              // 0=r, 1=z, 2=i_n, 3=h_n
      u16x8 a0,a1,a2, w00,w01,w02, w10,w11,w12, w20,w21,w22;
#define P1_ISSUE(ra,r0,r1,r2,is) do{ \
      const u16 *A_, *W_; int ld_, k0_; \
      if((is) < 2){ A_ = p.zb16 + (size_t)p1m0*128;  W_ = p.wih; ld_=128;  k0_=(is)*64; } \
      else        { A_ = hbi    + (size_t)p1m0*1024; W_ = p.whh; ld_=1024; k0_=((is)-2)*64; } \
      ra = ldc128(A_ + (size_t)ar*ld_ + k0_ + ac); \
      r0 = *(const u16x8*)(W_ + (size_t)(p1n0 + ar)*ld_        + k0_ + ac); \
      r1 = *(const u16x8*)(W_ + (size_t)(1024 + p1n0 + ar)*ld_ + k0_ + ac); \
      r2 = *(const u16x8*)(W_ + (size_t)(2048 + p1n0 + ar)*ld_ + k0_ + ac); \
    }while(0)
#define P1_STEP(ra,r0,r1,r2,it,nx) do{ \
      u16* b_ = smem + ((it)&1)*9216; \
      *(u16x8*)(b_ + ar*LDS_STRIDE + ac) = ra; \
      *(u16x8*)(b_ + 2304 + ar*LDS_STRIDE + ac) = r0; \
      *(u16x8*)(b_ + 4608 + ar*LDS_STRIDE + ac) = r1; \
      *(u16x8*)(b_ + 6912 + ar*LDS_STRIDE + ac) = r2; \
      asm volatile("s_waitcnt lgkmcnt(0)" ::: "memory"); \
      __builtin_amdgcn_s_barrier(); \
      __builtin_amdgcn_sched_barrier(0); \
      if((nx) < 18) P1_ISSUE(ra,r0,r1,r2,(nx)); \
      const int ai3_ = ((it) < 2) ? 2 : 3; \
      _Pragma("unroll") \
      for(int kc=0;kc<2;kc++){ \
        int ko = kc*32 + quad*8; \
        bf16x8 aa  = ldfrag(b_, wm*16 + l16, ko); \
        bf16x8 b0v = ldfrag(b_ + 2304, wn*16 + l16, ko); \
        bf16x8 b1v = ldfrag(b_ + 4608, wn*16 + l16, ko); \
        bf16x8 b2v = ldfrag(b_ + 6912, wn*16 + l16, ko); \
        acc[0]    = mfma16(aa,b0v,acc[0]); \
        acc[1]    = mfma16(aa,b1v,acc[1]); \
        acc[ai3_] = mfma16(aa,b2v,acc[ai3_]); \
      } \
    }while(0)
      P1_ISSUE(a0,w00,w01,w02,0);
      P1_ISSUE(a1,w10,w11,w12,1);
      P1_ISSUE(a2,w20,w21,w22,2);
#pragma unroll 1
      for(int ib=0; ib<18; ib+=3){
        P1_STEP(a0,w00,w01,w02, ib+0, ib+3);
        P1_STEP(a1,w10,w11,w12, ib+1, ib+4);
        P1_STEP(a2,w20,w21,w22, ib+2, ib+5);
      }
#undef P1_ISSUE
#undef P1_STEP
      __syncthreads();
#pragma unroll
      for(int i=0; i<4; i++){
        int m = p1m0 + wm*16 + quad*4 + i;
        int n = p1n;
        float r  = sigm (acc[0][i] + p.gbih[n]      + p.gbhh[n]);
        float z  = sigm (acc[1][i] + p.gbih[n+1024] + p.gbhh[n+1024]);
        float nn = tanhf(acc[2][i] + p.gbih[n+2048]
                         + r*(acc[3][i] + p.gbhh[n+2048]));
        float hv = (1.f-z)*nn + z*hreg[i];
        hreg[i] = hv;
        stc16(&hbo[(size_t)m*1024 + n], f2b(hv));
      }
    }
    gsync(p.bar, bi++, blk);

    // ========== P2: gate+prop hidden (2048 cols), 512 tiles 32m x 64n ======
    {
      const int m0 = (blk >> 5) * 32;
      const int n0 = (blk & 31) * 64;             // 0..1984
      const u16* W; const float* bias;
      if(n0 < 1024){ W = p.tgw + (size_t)n0*1024;        bias = p.tgb + n0; }
      else         { W = p.tpw + (size_t)(n0-1024)*1024; bias = p.tpb + (n0-1024); }
      mlp_tile(hbo + (size_t)m0*1024, W, bias, 1,
               p.Hbuf + (size_t)m0*2176 + n0, smem, tid);
    }
    gsync(p.bar, bi++, blk);

    // ========== P3: GP gemm (128 tiles 32x32, depth 4) + loc tiles =========
    if(blk < 128){
      const int m0 = (blk >> 3) * 32, n0 = (blk & 7) * 32;
      const int reg1 = (n0 >= 128);
      const u16*  A = p.Hbuf + (size_t)m0*2176 + (reg1 ? 1024 : 0);
      const u16*  W = reg1 ? p.tphzw + (size_t)(n0-128)*1024
                           : p.tghzw + (size_t)n0*1024;
      const float* bias = reg1 ? p.tphzb + (n0-128) : p.tghzb + n0;
      f32x4 acc3 = {};
      u16x8 a0,a1,a2,a3, q0,q1,q2,q3;
#define P3_ISSUE(ra,rw,is) do{ \
      ra = ldc128(A + (size_t)ar*2176 + (is)*64 + ac); \
      rw = *(const u16x8*)(W + (size_t)ar*1024 + (is)*64 + ac); \
    }while(0)
#define P3_STEP(ra,rw,it,nx) do{ \
      u16* b_ = smem + ((it)&1)*4608; \
      *(u16x8*)(b_ + ar*LDS_STRIDE + ac) = ra; \
      *(u16x8*)(b_ + 2304 + ar*LDS_STRIDE + ac) = rw; \
      asm volatile("s_waitcnt lgkmcnt(0)" ::: "memory"); \
      __builtin_amdgcn_s_barrier(); \
      __builtin_amdgcn_sched_barrier(0); \
      if((nx) < 16) P3_ISSUE(ra,rw,(nx)); \
      _Pragma("unroll") \
      for(int kc=0;kc<2;kc++){ \
        int ko = kc*32 + quad*8; \
        acc3 = mfma16(ldfrag(b_, wm*16 + l16, ko), \
                      ldfrag(b_ + 2304, wn*16 + l16, ko), acc3); \
      } \
    }while(0)
      P3_ISSUE(a0,q0,0); P3_ISSUE(a1,q1,1); P3_ISSUE(a2,q2,2); P3_ISSUE(a3,q3,3);
#pragma unroll 1
      for(int ib=0; ib<16; ib+=4){
        P3_STEP(a0,q0, ib+0, ib+4);
        P3_STEP(a1,q1, ib+1, ib+5);
        P3_STEP(a2,q2, ib+2, ib+6);
        P3_STEP(a3,q3, ib+3, ib+7);
      }
#undef P3_ISSUE
#undef P3_STEP
      __syncthreads();
#pragma unroll
      for(int i=0; i<4; i++){
        int m  = m0 + wm*16 + quad*4 + i;
        int cl = wn*16 + l16;
        stc32f(&p.GP[(size_t)m*256 + n0 + cl], acc3[i] + bias[cl]);
      }
    } else if(blk < 160){
      const int idx = blk - 128;
      const int m0  = (idx & 15) * 32;
      const int n0l = 2048 + (idx >> 4) * 64;
      mlp_tile(hbo + (size_t)m0*1024, p.tlw + (size_t)(n0l-2048)*1024,
               p.tlb + (n0l-2048), 0,
               p.Hbuf + (size_t)m0*2176 + n0l, smem, tid);
    }
    gsync(p.bar, bi++, blk);

    // ========== P4: z_t scale GEMM (K=128) + reparam, 64 tiles 16m x 64n ===
    if(blk < 64){
      const int m0 = (blk >> 1) * 16, n0 = (blk & 1) * 64;
      u16* lp = smem;                           // 16 x 136
      {
        int r = tid >> 4, c = (tid & 15) * 8;
        const float* src = p.GP + (size_t)(m0+r)*256 + 128 + c;
        union{u64 q; float f[2];} q0,q1,q2,q3;
        q0.q = ldc64(src);   q1.q = ldc64(src+2);
        q2.q = ldc64(src+4); q3.q = ldc64(src+6);
        u16x8 o;
        o[0]=f2b(fmaxf(q0.f[0],0.f)); o[1]=f2b(fmaxf(q0.f[1],0.f));
        o[2]=f2b(fmaxf(q1.f[0],0.f)); o[3]=f2b(fmaxf(q1.f[1],0.f));
        o[4]=f2b(fmaxf(q2.f[0],0.f)); o[5]=f2b(fmaxf(q2.f[1],0.f));
        o[6]=f2b(fmaxf(q3.f[0],0.f)); o[7]=f2b(fmaxf(q3.f[1],0.f));
        *(u16x8*)(lp + r*136 + c) = o;
      }
      __syncthreads();
      f32x4 acc4 = {};
      const int col = n0 + w*16 + l16;
#pragma unroll
      for(int kc=0; kc<4; kc++){
        int ko = kc*32 + quad*8;
        acc4 = mfma16(ldfragS(lp, l16, ko, 136),
                      ldw8b(p.tsw + (size_t)col*128 + ko), acc4);
      }
#pragma unroll
      for(int i=0; i<4; i++){
        int gm = m0 + quad*4 + i;
        float zs  = softp(acc4[i] + p.tsb[col]);
        float g   = sigm(ldc32f(&p.GP[(size_t)gm*256 + col]));
        float pv  = ldc32f(&p.GP[(size_t)gm*256 + 128 + col]);
        float loc = b2f(ldc16(&p.Hbuf[(size_t)gm*2176 + 2048 + col]));
        float zl  = (1.f-g)*loc + g*pv;
        float e   = p.eps[(size_t)gm*32768 + (size_t)t*128 + col];
        float zv  = zl + zs*e;
        p.out[(size_t)gm*32768 + (size_t)t*128 + col] = zv;
        stc16(&p.zb16[(size_t)gm*128 + col], f2b(zv));
      }
    }
    gsync(p.bar, bi++, blk);
  }
}

// ------------------- FUSED obs branch: one block = 32 rows ------------------
// grid 4096. Reads z (fp32) from out[b,t,0:128], overwrites with x_loc|x_scale.
#define LH_S 520
__global__ __launch_bounds__(256) void k_obs(
  const u16* __restrict__ ogw,   const float* __restrict__ ogb,
  const u16* __restrict__ oghzw, const float* __restrict__ oghzb,
  const u16* __restrict__ opw,   const float* __restrict__ opb,
  const u16* __restrict__ ophzw, const float* __restrict__ ophzb,
  const u16* __restrict__ olw,   const float* __restrict__ olb,
  const u16* __restrict__ osw,   const float* __restrict__ osb,
  float* __restrict__ out)
{
  __shared__ u16 lz[32*136];
  __shared__ u16 lh[32*LH_S];
  __shared__ u16 lp[32*72];
  const int r0 = blockIdx.x*32;
  const int t  = r0 >> 9, b0 = r0 & 511;        // 32 | 512 -> single t per block
  const int tid = threadIdx.x;
  const int lane = tid & 63, w = tid>>6, l16 = lane&15, quad = lane>>4;

#pragma unroll
  for(int i=0;i<2;i++){
    int ch = tid + i*256;
    int r = ch>>4, c = (ch&15)*8;
    const float* src = out + (size_t)(b0+r)*32768 + (size_t)t*128 + c;
    f32x4 p0 = *(const f32x4*)src, p1 = *(const f32x4*)(src+4);
    u16x8 o;
    o[0]=f2b(p0[0]); o[1]=f2b(p0[1]); o[2]=f2b(p0[2]); o[3]=f2b(p0[3]);
    o[4]=f2b(p1[0]); o[5]=f2b(p1[1]); o[6]=f2b(p1[2]); o[7]=f2b(p1[3]);
    *(u16x8*)(lz + r*136 + c) = o;
  }
  __syncthreads();

  f32x4 accp[2] = {}, accg[2] = {};
  const int col = w*16 + l16;                   // this wave's output column

#pragma unroll 1
  for(int ph=0; ph<2; ph++){                    // 0 = prop path, 1 = gate path
    const u16* hw = ph ? ogw   : opw;
    const float* hb = ph ? ogb : opb;
    const u16* zw = ph ? oghzw : ophzw;
    f32x4* acc2    = ph ? accg : accp;
#pragma unroll 1
    for(int c2=0; c2<2; c2++){                  // hidden cols [c2*512, +512)
      __syncthreads();                          // protect lh from prior readers
      for(int nt = w; nt < 32; nt += 4){
        int n = c2*512 + nt*16 + l16;           // hidden unit = weight row
#pragma unroll
        for(int mi=0; mi<2; mi++){
          f32x4 a = {};
#pragma unroll
          for(int kc=0;kc<4;kc++){
            int ko = kc*32 + quad*8;
            a = mfma16(ldfragS(lz, mi*16+l16, ko, 136),
                       ldw8b(hw + (size_t)n*128 + ko), a);
          }
          float bias = hb[n];
#pragma unroll
          for(int i=0;i<4;i++)
            lh[(mi*16+quad*4+i)*LH_S + nt*16 + l16] = f2b(fmaxf(a[i]+bias, 0.f));
        }
      }
      __syncthreads();
#pragma unroll
      for(int mi=0;mi<2;mi++){
        f32x4 a = acc2[mi];
        for(int kc=0;kc<16;kc++){
          int ko = kc*32 + quad*8;
          a = mfma16(ldfragS(lh, mi*16+l16, ko, LH_S),
                     ldw8b(zw + (size_t)col*1024 + c2*512 + ko), a);
        }
        acc2[mi] = a;
      }
    }
    if(ph==0){
      float bias = ophzb[col];
#pragma unroll
      for(int mi=0;mi<2;mi++)
#pragma unroll
      for(int i=0;i<4;i++){
        float pv = accp[mi][i] + bias;          // proposed incl. bias
        accp[mi][i] = pv;
        lp[(mi*16+quad*4+i)*72 + col] = f2b(fmaxf(pv, 0.f));
      }
    }
  }

  f32x4 accl[2]={}, accs[2]={};
#pragma unroll
  for(int mi=0;mi<2;mi++){
#pragma unroll
    for(int kc=0;kc<4;kc++){
      int ko=kc*32+quad*8;
      accl[mi]=mfma16(ldfragS(lz,mi*16+l16,ko,136),
                      ldw8b(olw + (size_t)col*128 + ko), accl[mi]);
    }
#pragma unroll
    for(int kc=0;kc<2;kc++){
      int ko=kc*32+quad*8;
      accs[mi]=mfma16(ldfragS(lp,mi*16+l16,ko,72),
                      ldw8b(osw + (size_t)col*64 + ko), accs[mi]);
    }
  }
#pragma unroll
  for(int mi=0;mi<2;mi++)
#pragma unroll
  for(int i=0;i<4;i++){
    int r = mi*16 + quad*4 + i;
    float g  = sigm(accg[mi][i] + oghzb[col]);
    float pv = accp[mi][i];
    float lc = accl[mi][i] + olb[col];
    float xs = softp(accs[mi][i] + osb[col]);
    float xl = (1.f-g)*lc + g*pv;
    size_t o = (size_t)(b0+r)*32768 + (size_t)t*128 + col;
    out[o]      = xl;
    out[o + 64] = xs;
  }
}

// ---------------------------------------------------------------------------
extern "C" void kernel_launch(void* const* d_in, const int* in_sizes, int n_in,
                              void* d_out, int out_size, void* d_ws, size_t ws_size,
                              hipStream_t stream)
{
  (void)in_sizes; (void)n_in; (void)out_size; (void)ws_size;
  const float* eps   = (const float*)d_in[1];
  const float* z0    = (const float*)d_in[2];
  const float* h0    = (const float*)d_in[3];
  const float* gwih  = (const float*)d_in[4];  const float* gbih  = (const float*)d_in[5];
  const float* gwhh  = (const float*)d_in[6];  const float* gbhh  = (const float*)d_in[7];
  const float* tgw   = (const float*)d_in[8];  const float* tgb   = (const float*)d_in[9];
  const float* tghzw = (const float*)d_in[10]; const float* tghzb = (const float*)d_in[11];
  const float* tpw   = (const float*)d_in[12]; const float* tpb   = (const float*)d_in[13];
  const float* tphzw = (const float*)d_in[14]; const float* tphzb = (const float*)d_in[15];
  const float* tlw   = (const float*)d_in[16]; const float* tlb   = (const float*)d_in[17];
  const float* tsw   = (const float*)d_in[18]; const float* tsb   = (const float*)d_in[19];
  const float* ogw   = (const float*)d_in[20]; const float* ogb   = (const float*)d_in[21];
  const float* oghzw = (const float*)d_in[22]; const float* oghzb = (const float*)d_in[23];
  const float* opw   = (const float*)d_in[24]; const float* opb   = (const float*)d_in[25];
  const float* ophzw = (const float*)d_in[26]; const float* ophzb = (const float*)d_in[27];
  const float* olw   = (const float*)d_in[28]; const float* olb   = (const float*)d_in[29];
  const float* osw   = (const float*)d_in[30]; const float* osb   = (const float*)d_in[31];
  float* out = (float*)d_out;

  // ---- ws layout (~17.9 MB total) ----
  char* ws = (char*)d_ws;
  size_t off = 0;
  u16*   Hbuf = (u16*)  (ws + off); off += (size_t)512*2176*2;     // 2.23 MB
  float* GP   = (float*)(ws + off); off += (size_t)512*256*4;      // 0.52 MB
  u16*   hb16 = (u16*)  (ws + off); off += (size_t)2*512*1024*2;   // 2.10 MB
  u16*   zb16 = (u16*)  (ws + off); off += (size_t)512*128*2;      // 0.13 MB
  u16* wc_gwih  = (u16*)(ws + off); off += (size_t)3072*128 *2;
  u16* wc_gwhh  = (u16*)(ws + off); off += (size_t)3072*1024*2;
  u16* wc_tgw   = (u16*)(ws + off); off += (size_t)1024*1024*2;
  u16* wc_tpw   = (u16*)(ws + off); off += (size_t)1024*1024*2;
  u16* wc_tlw   = (u16*)(ws + off); off += (size_t)128*1024 *2;
  u16* wc_tghzw = (u16*)(ws + off); off += (size_t)128*1024 *2;
  u16* wc_tphzw = (u16*)(ws + off); off += (size_t)128*1024 *2;
  u16* wc_tsw   = (u16*)(ws + off); off += (size_t)128*128  *2;
  u16* wc_ogw   = (u16*)(ws + off); off += (size_t)1024*128 *2;
  u16* wc_opw   = (u16*)(ws + off); off += (size_t)1024*128 *2;
  u16* wc_oghzw = (u16*)(ws + off); off += (size_t)64*1024  *2;
  u16* wc_ophzw = (u16*)(ws + off); off += (size_t)64*1024  *2;
  u16* wc_olw   = (u16*)(ws + off); off += (size_t)64*128   *2;
  u16* wc_osw   = (u16*)(ws + off); off += (size_t)64*64    *2;
  unsigned* bar = (unsigned*)(ws + off); off += 2048;              // barrier

  // ---- one-time weight conversion (per call; inputs may be re-poisoned) ----
  #define CVT(src, dst, n) k_cvt<<<(n)/2048, 256, 0, stream>>>((src), (dst))
  CVT(gwih,  wc_gwih,  3072*128);
  CVT(gwhh,  wc_gwhh,  3072*1024);
  CVT(tgw,   wc_tgw,   1024*1024);
  CVT(tpw,   wc_tpw,   1024*1024);
  CVT(tlw,   wc_tlw,   128*1024);
  CVT(tghzw, wc_tghzw, 128*1024);
  CVT(tphzw, wc_tphzw, 128*1024);
  CVT(tsw,   wc_tsw,   128*128);
  CVT(ogw,   wc_ogw,   1024*128);
  CVT(opw,   wc_opw,   1024*128);
  CVT(oghzw, wc_oghzw, 64*1024);
  CVT(ophzw, wc_ophzw, 64*1024);
  CVT(olw,   wc_olw,   64*128);
  CVT(osw,   wc_osw,   64*64);
  #undef CVT
  k_init <<<2048, 256, 0, stream>>>(hb16, zb16, h0, z0);
  k_bzero<<<1, 256, 0, stream>>>(bar);

  // ---- persistent recurrence (ordinary launch + software tree barrier) ----
  SeqP sp;
  sp.eps = eps; sp.h0 = h0; sp.z0 = z0;
  sp.gbih = gbih; sp.gbhh = gbhh;
  sp.tgb = tgb; sp.tpb = tpb; sp.tlb = tlb;
  sp.tghzb = tghzb; sp.tphzb = tphzb; sp.tsb = tsb;
  sp.wih = wc_gwih; sp.whh = wc_gwhh;
  sp.tgw = wc_tgw; sp.tpw = wc_tpw; sp.tlw = wc_tlw;
  sp.tghzw = wc_tghzw; sp.tphzw = wc_tphzw; sp.tsw = wc_tsw;
  sp.out = out; sp.GP = GP;
  sp.Hbuf = Hbuf; sp.hb16 = hb16; sp.zb16 = zb16;
  sp.bar = bar;
  k_seq<<<512, 256, 0, stream>>>(sp);

  // fused obs: reads z from out slices, overwrites them with x_loc|x_scale
  k_obs<<<4096, 256, 0, stream>>>(wc_ogw, ogb, wc_oghzw, oghzb,
                                  wc_opw, opb, wc_ophzw, ophzb,
                                  wc_olw, olb, wc_osw, osb, out);
}